// Round 5
// baseline (368.966 us; speedup 1.0000x reference)
//
#include <hip/hip_runtime.h>
#include <math.h>

// B=32, R=16384, C=16, IC=16, OC=16, 3 routing iterations.
// x: (B,C,IC) fp32 [8192]; W: (R,C,OC,IC) fp32 [67108864 = 256 MB]; out: (B,C,OC) fp32.
//
// Key algebra: logits are linear in v with the same u_hat each pass:
//   L2 = <u, v1>,  L3 = L2 + <u, v2> = <u, v1 + v2>
// so pass 3 is the SAME kernel as pass 2 fed with vs = v1 + v2 -> no L array.

#define RT 16384

typedef const __attribute__((address_space(1))) void GV;
typedef __attribute__((address_space(3))) void LV;

__device__ __forceinline__ float rfl(float v) {
    return __int_as_float(__builtin_amdgcn_readfirstlane(__float_as_int(v)));
}

// ---------------------------------------------------------------------------
// K0: zero the accumulator region (wsum+E2+Z2+E3+Z3 = 21504 floats).
// ---------------------------------------------------------------------------
__global__ __launch_bounds__(256) void k_zero(float* __restrict__ ws) {
    ws[blockIdx.x * 256 + threadIdx.x] = 0.f;      // grid 84 x 256 = 21504
}

// ---------------------------------------------------------------------------
// K1: wsum[c,o,i] = sum_r W[r,c,o,i].  W = 16,777,216 float4s.
// ---------------------------------------------------------------------------
__global__ __launch_bounds__(256) void k_wsum(const float4* __restrict__ W4,
                                              float* __restrict__ wsum) {
    int gid = blockIdx.x * 256 + threadIdx.x;      // [0, 262144)
    float4 acc = {0.f, 0.f, 0.f, 0.f};
    int idx = gid;
    #pragma unroll
    for (int it = 0; it < 64; ++it) {              // 16777216 / 262144 = 64
        float4 w = W4[idx];
        acc.x += w.x; acc.y += w.y; acc.z += w.z; acc.w += w.w;
        idx += 262144;
    }
    int cls = gid & 1023;                          // (c,o,i4) within an r-block
    atomicAdd(&wsum[cls * 4 + 0], acc.x);
    atomicAdd(&wsum[cls * 4 + 1], acc.y);
    atomicAdd(&wsum[cls * 4 + 2], acc.z);
    atomicAdd(&wsum[cls * 4 + 3], acc.w);
}

// ---------------------------------------------------------------------------
// K2: s1 = (1/R) * wsum . x ;  v1 = squash(s1)  -> v1[b*256 + c*16 + o]
// ---------------------------------------------------------------------------
__global__ __launch_bounds__(256) void k_v1(const float* __restrict__ wsum,
                                            const float* __restrict__ x,
                                            float* __restrict__ v1) {
    int t = blockIdx.x * 256 + threadIdx.x;        // 0..8191
    int o = t & 15, c = (t >> 4) & 15, b = t >> 8;
    const float* xb = x + (b * 16 + c) * 16;
    const float* wr = wsum + (c * 16 + o) * 16;
    float s = 0.f;
    #pragma unroll
    for (int i = 0; i < 16; ++i) s += wr[i] * xb[i];
    s *= (1.0f / 16384.0f);
    float ns = s * s;
    #pragma unroll
    for (int d = 1; d < 16; d <<= 1) ns += __shfl_xor(ns, d);
    v1[t] = s * (sqrtf(ns) / (1.0f + ns));
}

// ---------------------------------------------------------------------------
// K4a: v2 = squash(E/Z); vs = v1 + v2   (input to pass 3)
// ---------------------------------------------------------------------------
__global__ __launch_bounds__(256) void k_vout_vs(const float* __restrict__ E,
                                                 const float* __restrict__ Z,
                                                 const float* __restrict__ v1,
                                                 float* __restrict__ vs) {
    int t = blockIdx.x * 256 + threadIdx.x;        // 0..8191
    float s = E[t] / Z[t >> 4];                    // t>>4 = b*16+c
    float ns = s * s;
    #pragma unroll
    for (int d = 1; d < 16; d <<= 1) ns += __shfl_xor(ns, d);
    vs[t] = v1[t] + s * (sqrtf(ns) / (1.0f + ns));
}

// ---------------------------------------------------------------------------
// K4b: out = squash(E/Z)
// ---------------------------------------------------------------------------
__global__ __launch_bounds__(256) void k_vout(const float* __restrict__ E,
                                              const float* __restrict__ Z,
                                              float* __restrict__ dst) {
    int t = blockIdx.x * 256 + threadIdx.x;        // 0..8191
    float s = E[t] / Z[t >> 4];
    float ns = s * s;
    #pragma unroll
    for (int d = 1; d < 16; d <<= 1) ns += __shfl_xor(ns, d);
    dst[t] = s * (sqrtf(ns) / (1.0f + ns));
}

// ---------------------------------------------------------------------------
// K3: fused routing pass.  For each (b,c,r):
//   u[o] = sum_i W[r,c,o,i]*x[b,c,i];  Lv = sum_o u[o]*v[b,c,o]
//   e = exp(Lv);  E[b,c,o] += e*u[o];  Z[b,c] += e
//
// o-QUARTER layout (R4 post-mortem: 2 blocks/CU left k_iter stall-bound at
// 145 us vs the 51 us LDS-pipe floor; this version targets 4 blocks/CU and
// the 64-VGPR tier for 32 waves/CU):
//   lane = (h, lr): quarter h in [0,4) owns o in [4h,4h+4); lr in [0,16) =
//   row of a 16-row chunk.  Live VGPRs: u[4][4]+accE[4][4]+accZ+1 w-frag
//   + temps ~= 60 -> fits the 64-reg budget that __launch_bounds__(512,4)
//   empirically forces (R2: VGPR_Count=64).
//   LDS: 2 x 16 KB W double-buffer + 2 KB Vl = 34 KB -> 4 blocks/CU; the
//   whole (64,16) grid is co-resident (zero tail).
//   x in SGPRs (readfirstlane); v broadcast from LDS (1 float4/bl/chunk);
//   Lv = p + shfl_xor(16) + shfl_xor(32); accZ counted 4x -> x0.25.
//   global_load_lds width-16 staging, XOR swizzle on the GLOBAL source addr
//   (linear LDS dest); read addr = (lr*65 ^ h<<4) ^ m -> one v_xor per
//   ds_read_b128, optimal 8-lane-per-bank-group pattern (0 conflicts).
// ---------------------------------------------------------------------------
__global__ __launch_bounds__(512, 4)
void k_iter(const float* __restrict__ W,
            const float* __restrict__ x,
            const float* __restrict__ v,
            float* __restrict__ E,
            float* __restrict__ Z) {
    __shared__ float4 Wl[2][16 * 64];              // 32 KB: 2 x (16 rows x 1 KB)
    __shared__ float4 Vl[128];                     // v[b][o] for this c (2 KB)

    int c = blockIdx.y;
    int r0 = blockIdx.x * 256;
    int tid = threadIdx.x, wv = tid >> 6, lane = tid & 63;
    int h = lane >> 4, lr = lane & 15;             // o-quarter, row-in-chunk

    const float4* W4c = (const float4*)W + (size_t)c * 64;   // row r at +r*1024

    if (tid < 128) {                               // stage v block: Vl[b*4+j]
        int b = tid >> 2, j = tid & 3;
        Vl[tid] = ((const float4*)(v + (b * 16 + c) * 16))[j];
    }

    // x rows for this wave's 4 b's -> SGPRs (wave-uniform)
    float xs[4][16];
    #pragma unroll
    for (int bl = 0; bl < 4; ++bl) {
        const float4* xb = (const float4*)(x + ((wv * 4 + bl) * 16 + c) * 16);
        #pragma unroll
        for (int j = 0; j < 4; ++j) {
            float4 xv = xb[j];
            xs[bl][j * 4 + 0] = rfl(xv.x);
            xs[bl][j * 4 + 1] = rfl(xv.y);
            xs[bl][j * 4 + 2] = rfl(xv.z);
            xs[bl][j * 4 + 3] = rfl(xv.w);
        }
    }

    float accE[4][4];
    float accZ[4] = {0.f, 0.f, 0.f, 0.f};
    #pragma unroll
    for (int bl = 0; bl < 4; ++bl)
        #pragma unroll
        for (int q = 0; q < 4; ++q) accE[bl][q] = 0.f;

    // stage chunk cn (16 rows = 16 KB) into buffer tb: 2 rows per wave
#define STAGE(tb, cn) {                                                        \
        int rb = r0 + (cn) * 16;                                               \
        _Pragma("unroll")                                                      \
        for (int k = 0; k < 2; ++k) {                                          \
            int row = k * 8 + wv;                                              \
            const float4* src = W4c + (size_t)(rb + row) * 1024 + (lane ^ row);\
            __builtin_amdgcn_global_load_lds((GV*)src,                         \
                (LV*)&Wl[tb][row * 64], 16, 0, 0);                             \
        } }

    STAGE(0, 0);
    __syncthreads();

    int vlidx = (lr * 65) ^ (h << 4);              // swizzled read base (float4 idx)

    #pragma unroll 2
    for (int chunk = 0; chunk < 16; ++chunk) {
        int buf = chunk & 1;
        if (chunk < 15) STAGE(buf ^ 1, chunk + 1); // prefetch next (in flight)

        const float4* Wlb = &Wl[buf][0];
        float u[4][4];
        #pragma unroll
        for (int q = 0; q < 4; ++q) {              // q = o within quarter
            #pragma unroll
            for (int bl = 0; bl < 4; ++bl) u[bl][q] = 0.f;
            #pragma unroll
            for (int j = 0; j < 4; ++j) {          // j = i-group
                float4 w = Wlb[vlidx ^ (q * 4 + j)];
                #pragma unroll
                for (int bl = 0; bl < 4; ++bl)
                    u[bl][q] += w.x * xs[bl][j * 4 + 0] + w.y * xs[bl][j * 4 + 1] +
                                w.z * xs[bl][j * 4 + 2] + w.w * xs[bl][j * 4 + 3];
            }
        }

        #pragma unroll
        for (int bl = 0; bl < 4; ++bl) {
            float4 vb = Vl[(wv * 4 + bl) * 4 + h]; // this quarter's 4 v comps
            float p = u[bl][0] * vb.x + u[bl][1] * vb.y +
                      u[bl][2] * vb.z + u[bl][3] * vb.w;
            float t = p + __shfl_xor(p, 16);       // combine 4 o-quarters
            float Lv = t + __shfl_xor(t, 32);
            float e = __expf(Lv);
            accZ[bl] += e;                         // counted 4x (all quarters)
            #pragma unroll
            for (int q = 0; q < 4; ++q) accE[bl][q] += e * u[bl][q];
        }
        __syncthreads();
    }
#undef STAGE

    // Reduce accE over the 16 rows (butterfly d<16 stays within each quarter).
    float va = 0.f;
    #pragma unroll
    for (int bl = 0; bl < 4; ++bl) {
        #pragma unroll
        for (int q = 0; q < 4; ++q) {
            float t = accE[bl][q];
            #pragma unroll
            for (int d = 1; d < 16; d <<= 1) t += __shfl_xor(t, d);
            if (lr == bl * 4 + q) va = t;
        }
    }
    float vz = 0.f;
    #pragma unroll
    for (int bl = 0; bl < 4; ++bl) {
        float t = accZ[bl];
        #pragma unroll
        for (int d = 1; d < 64; d <<= 1) t += __shfl_xor(t, d);
        if (lane == bl) vz = t;
    }
    int b = wv * 4 + (lr >> 2);
    int o = h * 4 + (lr & 3);
    atomicAdd(&E[b * 256 + c * 16 + o], va);
    if (lane < 4) atomicAdd(&Z[(wv * 4 + lane) * 16 + c], vz * 0.25f);
}

// ---------------------------------------------------------------------------
// launch
// ---------------------------------------------------------------------------
extern "C" void kernel_launch(void* const* d_in, const int* in_sizes, int n_in,
                              void* d_out, int out_size, void* d_ws, size_t ws_size,
                              hipStream_t stream) {
    const float* x = (const float*)d_in[0];        // 8192 floats
    const float* W = (const float*)d_in[1];        // 67108864 floats (256 MB)
    float* out = (float*)d_out;                    // 8192 floats
    float* ws = (float*)d_ws;

    float* wsum = ws + 0;          // 4096
    float* E2   = ws + 4096;       // 8192
    float* Z2   = ws + 12288;      // 512
    float* E3   = ws + 12800;      // 8192
    float* Z3   = ws + 20992;      // 512   (accumulated region ends at 21504)
    float* v1   = ws + 21504;      // 8192
    float* vs   = ws + 29696;      // 8192  (v1 + v2, input to pass 3)

    // zero accumulators with our own kernel
    k_zero<<<84, 256, 0, stream>>>(ws);            // 84*256 = 21504 floats

    // iter 1: uniform softmax -> v1 from Wsum (W pass 1)
    k_wsum<<<1024, 256, 0, stream>>>((const float4*)W, wsum);
    k_v1<<<32, 256, 0, stream>>>(wsum, x, v1);

    // iter 2 fused: L2 = <u, v1>, E2/Z2 accumulated in-pass (W pass 2)
    k_iter<<<dim3(64, 16), 512, 0, stream>>>(W, x, v1, E2, Z2);
    k_vout_vs<<<32, 256, 0, stream>>>(E2, Z2, v1, vs);   // vs = v1 + squash(E2/Z2)

    // iter 3 fused: L3 = <u, v1+v2> (linearity: no history buffer needed)
    k_iter<<<dim3(64, 16), 512, 0, stream>>>(W, x, vs, E3, Z3);
    k_vout<<<32, 256, 0, stream>>>(E3, Z3, out);         // out = squash(E3/Z3)
}

// Round 6
// 280.034 us; speedup vs baseline: 1.3176x; 1.3176x over previous
//
#include <hip/hip_runtime.h>
#include <math.h>

// B=32, R=16384, C=16, IC=16, OC=16, 3 routing iterations.
// x: (B,C,IC) fp32 [8192]; W: (R,C,OC,IC) fp32 [67108864 = 256 MB]; out: (B,C,OC) fp32.
//
// Key algebra: logits are linear in v with the same u_hat each pass:
//   L2 = <u, v1>,  L3 = L2 + <u, v2> = <u, v1 + v2>
// so pass 3 is the SAME kernel as pass 2 fed with vs = v1 + v2 -> no L array.

#define RT 16384

typedef const __attribute__((address_space(1))) void GV;
typedef __attribute__((address_space(3))) void LV;

__device__ __forceinline__ float rfl(float v) {
    return __int_as_float(__builtin_amdgcn_readfirstlane(__float_as_int(v)));
}

// ---------------------------------------------------------------------------
// K0: zero the accumulator region (wsum+E2+Z2+E3+Z3 = 21504 floats).
// ---------------------------------------------------------------------------
__global__ __launch_bounds__(256) void k_zero(float* __restrict__ ws) {
    ws[blockIdx.x * 256 + threadIdx.x] = 0.f;      // grid 84 x 256 = 21504
}

// ---------------------------------------------------------------------------
// K1: wsum[c,o,i] = sum_r W[r,c,o,i].  W = 16,777,216 float4s.
// ---------------------------------------------------------------------------
__global__ __launch_bounds__(256) void k_wsum(const float4* __restrict__ W4,
                                              float* __restrict__ wsum) {
    int gid = blockIdx.x * 256 + threadIdx.x;      // [0, 262144)
    float4 acc = {0.f, 0.f, 0.f, 0.f};
    int idx = gid;
    #pragma unroll
    for (int it = 0; it < 64; ++it) {              // 16777216 / 262144 = 64
        float4 w = W4[idx];
        acc.x += w.x; acc.y += w.y; acc.z += w.z; acc.w += w.w;
        idx += 262144;
    }
    int cls = gid & 1023;                          // (c,o,i4) within an r-block
    atomicAdd(&wsum[cls * 4 + 0], acc.x);
    atomicAdd(&wsum[cls * 4 + 1], acc.y);
    atomicAdd(&wsum[cls * 4 + 2], acc.z);
    atomicAdd(&wsum[cls * 4 + 3], acc.w);
}

// ---------------------------------------------------------------------------
// K2: s1 = (1/R) * wsum . x ;  v1 = squash(s1)  -> v1[b*256 + c*16 + o]
// ---------------------------------------------------------------------------
__global__ __launch_bounds__(256) void k_v1(const float* __restrict__ wsum,
                                            const float* __restrict__ x,
                                            float* __restrict__ v1) {
    int t = blockIdx.x * 256 + threadIdx.x;        // 0..8191
    int o = t & 15, c = (t >> 4) & 15, b = t >> 8;
    const float* xb = x + (b * 16 + c) * 16;
    const float* wr = wsum + (c * 16 + o) * 16;
    float s = 0.f;
    #pragma unroll
    for (int i = 0; i < 16; ++i) s += wr[i] * xb[i];
    s *= (1.0f / 16384.0f);
    float ns = s * s;
    #pragma unroll
    for (int d = 1; d < 16; d <<= 1) ns += __shfl_xor(ns, d);
    v1[t] = s * (sqrtf(ns) / (1.0f + ns));
}

// ---------------------------------------------------------------------------
// K4a: v2 = squash(E/Z); vs = v1 + v2   (input to pass 3)
// ---------------------------------------------------------------------------
__global__ __launch_bounds__(256) void k_vout_vs(const float* __restrict__ E,
                                                 const float* __restrict__ Z,
                                                 const float* __restrict__ v1,
                                                 float* __restrict__ vs) {
    int t = blockIdx.x * 256 + threadIdx.x;        // 0..8191
    float s = E[t] / Z[t >> 4];                    // t>>4 = b*16+c
    float ns = s * s;
    #pragma unroll
    for (int d = 1; d < 16; d <<= 1) ns += __shfl_xor(ns, d);
    vs[t] = v1[t] + s * (sqrtf(ns) / (1.0f + ns));
}

// ---------------------------------------------------------------------------
// K4b: out = squash(E/Z)
// ---------------------------------------------------------------------------
__global__ __launch_bounds__(256) void k_vout(const float* __restrict__ E,
                                              const float* __restrict__ Z,
                                              float* __restrict__ dst) {
    int t = blockIdx.x * 256 + threadIdx.x;        // 0..8191
    float s = E[t] / Z[t >> 4];
    float ns = s * s;
    #pragma unroll
    for (int d = 1; d < 16; d <<= 1) ns += __shfl_xor(ns, d);
    dst[t] = s * (sqrtf(ns) / (1.0f + ns));
}

// ---------------------------------------------------------------------------
// K3: fused routing pass (counted-vmcnt pipeline, T3+T4).
//   u[o] = sum_i W[r,c,o,i]*x[b,c,i];  Lv = sum_o u[o]*v[b,c,o]
//   e = exp(Lv);  E[b,c,o] += e*u[o];  Z[b,c] += e
//
// R5 post-mortem: the __syncthreads() per chunk drains vmcnt(0), so the
// "double buffer" never had loads in flight across a barrier -> 157 us vs a
// ~45 us pipe floor.  This version:
//   - 4 x 16 KB ring buffer (66 KB LDS, 2 blocks/CU), prefetch distance 2
//   - raw s_barrier with counted s_waitcnt vmcnt(2): each wave issues exactly
//     2 global_load_lds per chunk, so vmcnt(2) retires chunk k+1's loads
//     (issued at k-1) while chunk k+2's stay in flight ACROSS the barrier
//   - chunk loop fully unrolled -> exact tail waits (vmcnt(0) at 14)
//   - vmcnt(0) pin after xs/Vl loads keeps the counts exact
//   - __launch_bounds__(512): LDS limits to 2 blocks/CU (4 waves/SIMD), so
//     the 128-reg budget is free -- no spill risk under full unroll
// Quarter layout as R5 (verified 0 bank conflicts): lane=(h,lr), quarter h
// owns o in [4h,4h+4), row lr of a 16-row chunk; x in SGPRs; v from LDS;
// Lv = p + shfl16 + shfl32; accZ counted 4x -> x0.25.
// ---------------------------------------------------------------------------
__global__ __launch_bounds__(512)
void k_iter(const float* __restrict__ W,
            const float* __restrict__ x,
            const float* __restrict__ v,
            float* __restrict__ E,
            float* __restrict__ Z) {
    __shared__ float4 Wl[4][16 * 64];              // 64 KB ring: 4 x (16 rows x 1 KB)
    __shared__ float4 Vl[128];                     // v[b][o] for this c (2 KB)

    int c = blockIdx.y;
    int r0 = blockIdx.x * 256;
    int tid = threadIdx.x, wv = tid >> 6, lane = tid & 63;
    int h = lane >> 4, lr = lane & 15;             // o-quarter, row-in-chunk

    const float4* W4c = (const float4*)W + (size_t)c * 64;   // row r at +r*1024

    if (tid < 128) {                               // stage v block: Vl[b*4+j]
        int b = tid >> 2, j = tid & 3;
        Vl[tid] = ((const float4*)(v + (b * 16 + c) * 16))[j];
    }

    // x rows for this wave's 4 b's -> SGPRs (wave-uniform)
    float xs[4][16];
    #pragma unroll
    for (int bl = 0; bl < 4; ++bl) {
        const float4* xb = (const float4*)(x + ((wv * 4 + bl) * 16 + c) * 16);
        #pragma unroll
        for (int j = 0; j < 4; ++j) {
            float4 xv = xb[j];
            xs[bl][j * 4 + 0] = rfl(xv.x);
            xs[bl][j * 4 + 1] = rfl(xv.y);
            xs[bl][j * 4 + 2] = rfl(xv.z);
            xs[bl][j * 4 + 3] = rfl(xv.w);
        }
    }
    // pin vmcnt=0 so the counted waits below are exact (xs/Vl loads retired)
    asm volatile("s_waitcnt vmcnt(0)" ::: "memory");

    float accE[4][4];
    float accZ[4] = {0.f, 0.f, 0.f, 0.f};
    #pragma unroll
    for (int bl = 0; bl < 4; ++bl)
        #pragma unroll
        for (int q = 0; q < 4; ++q) accE[bl][q] = 0.f;

    // stage chunk cn (16 rows = 16 KB) into ring slot tb: 2 rows per wave
#define STAGE(tb, cn) {                                                        \
        int rb = r0 + (cn) * 16;                                               \
        _Pragma("unroll")                                                      \
        for (int k = 0; k < 2; ++k) {                                          \
            int row = k * 8 + wv;                                              \
            const float4* src = W4c + (size_t)(rb + row) * 1024 + (lane ^ row);\
            __builtin_amdgcn_global_load_lds((GV*)src,                         \
                (LV*)&Wl[tb][row * 64], 16, 0, 0);                             \
        } }

    // prologue: stage chunks 0,1; wait chunk 0 (vmcnt(2): chunk 1 stays in flight)
    STAGE(0, 0);
    STAGE(1, 1);
    asm volatile("s_waitcnt vmcnt(2) lgkmcnt(0)\n\ts_barrier" ::: "memory");

    int vlidx = (lr * 65) ^ (h << 4);              // swizzled read base (float4 idx)

    #pragma unroll
    for (int chunk = 0; chunk < 16; ++chunk) {
        if (chunk < 14) STAGE((chunk + 2) & 3, chunk + 2);   // prefetch distance 2

        const float4* Wlb = &Wl[chunk & 3][0];
        float u[4][4];
        #pragma unroll
        for (int q = 0; q < 4; ++q) {              // q = o within quarter
            #pragma unroll
            for (int bl = 0; bl < 4; ++bl) u[bl][q] = 0.f;
            #pragma unroll
            for (int j = 0; j < 4; ++j) {          // j = i-group
                float4 w = Wlb[vlidx ^ (q * 4 + j)];
                #pragma unroll
                for (int bl = 0; bl < 4; ++bl)
                    u[bl][q] += w.x * xs[bl][j * 4 + 0] + w.y * xs[bl][j * 4 + 1] +
                                w.z * xs[bl][j * 4 + 2] + w.w * xs[bl][j * 4 + 3];
            }
        }

        #pragma unroll
        for (int bl = 0; bl < 4; ++bl) {
            float4 vb = Vl[(wv * 4 + bl) * 4 + h]; // this quarter's 4 v comps
            float p = u[bl][0] * vb.x + u[bl][1] * vb.y +
                      u[bl][2] * vb.z + u[bl][3] * vb.w;
            float t = p + __shfl_xor(p, 16);       // combine 4 o-quarters
            float Lv = t + __shfl_xor(t, 32);
            float e = __expf(Lv);
            accZ[bl] += e;                         // counted 4x (all quarters)
            #pragma unroll
            for (int q = 0; q < 4; ++q) accE[bl][q] += e * u[bl][q];
        }

        // counted wait: retire chunk k+1's loads, keep chunk k+2's in flight
        if (chunk < 14)
            asm volatile("s_waitcnt vmcnt(2) lgkmcnt(0)\n\ts_barrier" ::: "memory");
        else if (chunk == 14)
            asm volatile("s_waitcnt vmcnt(0) lgkmcnt(0)\n\ts_barrier" ::: "memory");
        // chunk 15: last compute -> straight to epilogue, no barrier needed
    }
#undef STAGE

    // Reduce accE over the 16 rows (butterfly d<16 stays within each quarter).
    float va = 0.f;
    #pragma unroll
    for (int bl = 0; bl < 4; ++bl) {
        #pragma unroll
        for (int q = 0; q < 4; ++q) {
            float t = accE[bl][q];
            #pragma unroll
            for (int d = 1; d < 16; d <<= 1) t += __shfl_xor(t, d);
            if (lr == bl * 4 + q) va = t;
        }
    }
    float vz = 0.f;
    #pragma unroll
    for (int bl = 0; bl < 4; ++bl) {
        float t = accZ[bl];
        #pragma unroll
        for (int d = 1; d < 64; d <<= 1) t += __shfl_xor(t, d);
        if (lane == bl) vz = t;
    }
    int b = wv * 4 + (lr >> 2);
    int o = h * 4 + (lr & 3);
    atomicAdd(&E[b * 256 + c * 16 + o], va);
    if (lane < 4) atomicAdd(&Z[(wv * 4 + lane) * 16 + c], vz * 0.25f);
}

// ---------------------------------------------------------------------------
// launch
// ---------------------------------------------------------------------------
extern "C" void kernel_launch(void* const* d_in, const int* in_sizes, int n_in,
                              void* d_out, int out_size, void* d_ws, size_t ws_size,
                              hipStream_t stream) {
    const float* x = (const float*)d_in[0];        // 8192 floats
    const float* W = (const float*)d_in[1];        // 67108864 floats (256 MB)
    float* out = (float*)d_out;                    // 8192 floats
    float* ws = (float*)d_ws;

    float* wsum = ws + 0;          // 4096
    float* E2   = ws + 4096;       // 8192
    float* Z2   = ws + 12288;      // 512
    float* E3   = ws + 12800;      // 8192
    float* Z3   = ws + 20992;      // 512   (accumulated region ends at 21504)
    float* v1   = ws + 21504;      // 8192
    float* vs   = ws + 29696;      // 8192  (v1 + v2, input to pass 3)

    // zero accumulators with our own kernel
    k_zero<<<84, 256, 0, stream>>>(ws);            // 84*256 = 21504 floats

    // iter 1: uniform softmax -> v1 from Wsum (W pass 1)
    k_wsum<<<1024, 256, 0, stream>>>((const float4*)W, wsum);
    k_v1<<<32, 256, 0, stream>>>(wsum, x, v1);

    // iter 2 fused: L2 = <u, v1>, E2/Z2 accumulated in-pass (W pass 2)
    k_iter<<<dim3(64, 16), 512, 0, stream>>>(W, x, v1, E2, Z2);
    k_vout_vs<<<32, 256, 0, stream>>>(E2, Z2, v1, vs);   // vs = v1 + squash(E2/Z2)

    // iter 3 fused: L3 = <u, v1+v2> (linearity: no history buffer needed)
    k_iter<<<dim3(64, 16), 512, 0, stream>>>(W, x, vs, E3, Z3);
    k_vout<<<32, 256, 0, stream>>>(E3, Z3, out);         // out = squash(E3/Z3)
}

// Round 7
// 270.653 us; speedup vs baseline: 1.3632x; 1.0347x over previous
//
#include <hip/hip_runtime.h>
#include <math.h>

// B=32, R=16384, C=16, IC=16, OC=16, 3 routing iterations.
// x: (B,C,IC) fp32 [8192]; W: (R,C,OC,IC) fp32 [67108864 = 256 MB]; out: (B,C,OC) fp32.
//
// Key algebra: logits are linear in v with the same u_hat each pass:
//   L2 = <u, v1>,  L3 = L2 + <u, v2> = <u, v1 + v2>
// so pass 3 is the SAME kernel as pass 2 fed with vs = v1 + v2 -> no L array.

#define RT 16384

typedef const __attribute__((address_space(1))) void GV;
typedef __attribute__((address_space(3))) void LV;

__device__ __forceinline__ float rfl(float v) {
    return __int_as_float(__builtin_amdgcn_readfirstlane(__float_as_int(v)));
}

// ---------------------------------------------------------------------------
// K0: zero the accumulator region (wsum+E2+Z2+E3+Z3 = 21504 floats).
// ---------------------------------------------------------------------------
__global__ __launch_bounds__(256) void k_zero(float* __restrict__ ws) {
    ws[blockIdx.x * 256 + threadIdx.x] = 0.f;      // grid 84 x 256 = 21504
}

// ---------------------------------------------------------------------------
// K1: wsum[c,o,i] = sum_r W[r,c,o,i].  W = 16,777,216 float4s.
// ---------------------------------------------------------------------------
__global__ __launch_bounds__(256) void k_wsum(const float4* __restrict__ W4,
                                              float* __restrict__ wsum) {
    int gid = blockIdx.x * 256 + threadIdx.x;      // [0, 262144)
    float4 acc = {0.f, 0.f, 0.f, 0.f};
    int idx = gid;
    #pragma unroll
    for (int it = 0; it < 64; ++it) {              // 16777216 / 262144 = 64
        float4 w = W4[idx];
        acc.x += w.x; acc.y += w.y; acc.z += w.z; acc.w += w.w;
        idx += 262144;
    }
    int cls = gid & 1023;                          // (c,o,i4) within an r-block
    atomicAdd(&wsum[cls * 4 + 0], acc.x);
    atomicAdd(&wsum[cls * 4 + 1], acc.y);
    atomicAdd(&wsum[cls * 4 + 2], acc.z);
    atomicAdd(&wsum[cls * 4 + 3], acc.w);
}

// ---------------------------------------------------------------------------
// K2: s1 = (1/R) * wsum . x ;  v1 = squash(s1)  -> v1[b*256 + c*16 + o]
// ---------------------------------------------------------------------------
__global__ __launch_bounds__(256) void k_v1(const float* __restrict__ wsum,
                                            const float* __restrict__ x,
                                            float* __restrict__ v1) {
    int t = blockIdx.x * 256 + threadIdx.x;        // 0..8191
    int o = t & 15, c = (t >> 4) & 15, b = t >> 8;
    const float* xb = x + (b * 16 + c) * 16;
    const float* wr = wsum + (c * 16 + o) * 16;
    float s = 0.f;
    #pragma unroll
    for (int i = 0; i < 16; ++i) s += wr[i] * xb[i];
    s *= (1.0f / 16384.0f);
    float ns = s * s;
    #pragma unroll
    for (int d = 1; d < 16; d <<= 1) ns += __shfl_xor(ns, d);
    v1[t] = s * (sqrtf(ns) / (1.0f + ns));
}

// ---------------------------------------------------------------------------
// K4a: v2 = squash(E/Z); vs = v1 + v2   (input to pass 3)
// ---------------------------------------------------------------------------
__global__ __launch_bounds__(256) void k_vout_vs(const float* __restrict__ E,
                                                 const float* __restrict__ Z,
                                                 const float* __restrict__ v1,
                                                 float* __restrict__ vs) {
    int t = blockIdx.x * 256 + threadIdx.x;        // 0..8191
    float s = E[t] / Z[t >> 4];                    // t>>4 = b*16+c
    float ns = s * s;
    #pragma unroll
    for (int d = 1; d < 16; d <<= 1) ns += __shfl_xor(ns, d);
    vs[t] = v1[t] + s * (sqrtf(ns) / (1.0f + ns));
}

// ---------------------------------------------------------------------------
// K4b: out = squash(E/Z)
// ---------------------------------------------------------------------------
__global__ __launch_bounds__(256) void k_vout(const float* __restrict__ E,
                                              const float* __restrict__ Z,
                                              float* __restrict__ dst) {
    int t = blockIdx.x * 256 + threadIdx.x;        // 0..8191
    float s = E[t] / Z[t >> 4];
    float ns = s * s;
    #pragma unroll
    for (int d = 1; d < 16; d <<= 1) ns += __shfl_xor(ns, d);
    dst[t] = s * (sqrtf(ns) / (1.0f + ns));
}

// ---------------------------------------------------------------------------
// K3: fused routing pass (padded-stride LDS + ring-3 counted-vmcnt pipeline).
//   u[o] = sum_i W[r,c,o,i]*x[b,c,i];  Lv = sum_o u[o]*v[b,c,o]
//   e = exp(Lv);  E[b,c,o] += e*u[o];  Z[b,c] += e
//
// R6 post-mortem: counted vmcnt only bought 12%; the stall is LDS-pipe +
// address-calc VALU + low occupancy (2 blocks/CU).  This version:
//   - PADDED rows: 65 float4/row (1040B).  Bank granule = (65*lr+16h+n)%8 =
//     (lr+n)%8 -> same 8-lanes-per-16B-group pattern as the verified XOR
//     scheme (0 conflicts), but offsets are ADDITIVE: every ds_read_b128
//     gets a compile-time immediate (slot*16640 + n*16 <= 33.5KB), ZERO
//     per-read VALU; staging is a plain linear 1KB row DMA (no src swizzle).
//   - ring-3 x 16.25KB = 50.75KB LDS -> 3 blocks/CU (6 waves/SIMD); counted
//     s_waitcnt vmcnt(2), prefetch distance 2 (slot (k+2)%3 is 2 barriers
//     past its last reader -> race-free).
//   - __launch_bounds__(512,6): 80-VGPR tier.  Live set ~62-75 (u direct-
//     init, no addr math, Vl broadcast-read in-loop).  WRITE_SIZE is the
//     spill canary.
// Quarter layout: lane=(h,lr), quarter h owns o in [4h,4h+4), row lr of a
// 16-row chunk; x in SGPRs; Lv = p + shfl16 + shfl32; accZ x0.25.
// ---------------------------------------------------------------------------
#define ROWF4  65
#define SLOTF4 (16 * ROWF4)                        // 1040 float4 = 16640 B

__global__ __launch_bounds__(512, 6)
void k_iter(const float* __restrict__ W,
            const float* __restrict__ x,
            const float* __restrict__ v,
            float* __restrict__ E,
            float* __restrict__ Z) {
    __shared__ float4 Wl[3 * SLOTF4];              // 48.75 KB ring of 3 slots
    __shared__ float4 Vl[128];                     // v[b][o] for this c (2 KB)

    int c = blockIdx.y;
    int r0 = blockIdx.x * 256;
    int tid = threadIdx.x, wv = tid >> 6, lane = tid & 63;
    int h = lane >> 4, lr = lane & 15;             // o-quarter, row-in-chunk

    const float4* W4c = (const float4*)W + (size_t)c * 64;   // row r at +r*1024

    if (tid < 128) {                               // stage v block: Vl[b*4+j]
        int b = tid >> 2, j = tid & 3;
        Vl[tid] = ((const float4*)(v + (b * 16 + c) * 16))[j];
    }

    // x rows for this wave's 4 b's -> SGPRs (wave-uniform)
    float xs[4][16];
    #pragma unroll
    for (int bl = 0; bl < 4; ++bl) {
        const float4* xb = (const float4*)(x + ((wv * 4 + bl) * 16 + c) * 16);
        #pragma unroll
        for (int j = 0; j < 4; ++j) {
            float4 xv = xb[j];
            xs[bl][j * 4 + 0] = rfl(xv.x);
            xs[bl][j * 4 + 1] = rfl(xv.y);
            xs[bl][j * 4 + 2] = rfl(xv.z);
            xs[bl][j * 4 + 3] = rfl(xv.w);
        }
    }
    // pin vmcnt=0 so the counted waits below are exact (x/Vl loads retired)
    asm volatile("s_waitcnt vmcnt(0)" ::: "memory");

    float accE[4][4];
    float accZ[4] = {0.f, 0.f, 0.f, 0.f};
    #pragma unroll
    for (int bl = 0; bl < 4; ++bl)
        #pragma unroll
        for (int q = 0; q < 4; ++q) accE[bl][q] = 0.f;

    // stage chunk cn (16 rows, 1KB each) into ring slot sl: 2 rows per wave,
    // linear DMA into the padded row (1024B written, 16B pad untouched)
#define STAGE(sl, cn) {                                                        \
        int rb = r0 + (cn) * 16;                                               \
        _Pragma("unroll")                                                      \
        for (int k = 0; k < 2; ++k) {                                          \
            int row = k * 8 + wv;                                              \
            const float4* src = W4c + (size_t)(rb + row) * 1024 + lane;        \
            __builtin_amdgcn_global_load_lds((GV*)src,                         \
                (LV*)&Wl[(sl) * SLOTF4 + row * ROWF4], 16, 0, 0);              \
        } }

    // prologue: stage chunks 0,1; wait chunk 0 (vmcnt(2): chunk 1 in flight)
    STAGE(0, 0);
    STAGE(1, 1);
    asm volatile("s_waitcnt vmcnt(2) lgkmcnt(0)\n\ts_barrier" ::: "memory");

    int vidx = lr * ROWF4 + h * 16;                // per-lane read base (f4 idx)

    #pragma unroll
    for (int chunk = 0; chunk < 16; ++chunk) {
        if (chunk < 14) STAGE((chunk + 2) % 3, chunk + 2);   // distance-2 prefetch

        const int sbase = (chunk % 3) * SLOTF4;    // compile-time (full unroll)
        float u[4][4];
        #pragma unroll
        for (int q = 0; q < 4; ++q) {              // q = o within quarter
            float4 w0 = Wl[sbase + vidx + q * 4 + 0];   // imm-offset ds_read_b128
            float4 w1 = Wl[sbase + vidx + q * 4 + 1];
            float4 w2 = Wl[sbase + vidx + q * 4 + 2];
            float4 w3 = Wl[sbase + vidx + q * 4 + 3];
            #pragma unroll
            for (int bl = 0; bl < 4; ++bl) {
                u[bl][q] =
                    w0.x*xs[bl][0]  + w0.y*xs[bl][1]  + w0.z*xs[bl][2]  + w0.w*xs[bl][3]  +
                    w1.x*xs[bl][4]  + w1.y*xs[bl][5]  + w1.z*xs[bl][6]  + w1.w*xs[bl][7]  +
                    w2.x*xs[bl][8]  + w2.y*xs[bl][9]  + w2.z*xs[bl][10] + w2.w*xs[bl][11] +
                    w3.x*xs[bl][12] + w3.y*xs[bl][13] + w3.z*xs[bl][14] + w3.w*xs[bl][15];
            }
        }

        #pragma unroll
        for (int bl = 0; bl < 4; ++bl) {
            float4 vb = Vl[(wv * 4 + bl) * 4 + h]; // this quarter's 4 v comps
            float p = u[bl][0] * vb.x + u[bl][1] * vb.y +
                      u[bl][2] * vb.z + u[bl][3] * vb.w;
            float t = p + __shfl_xor(p, 16);       // combine 4 o-quarters
            float Lv = t + __shfl_xor(t, 32);
            float e = __expf(Lv);
            accZ[bl] += e;                         // counted 4x (all quarters)
            #pragma unroll
            for (int q = 0; q < 4; ++q) accE[bl][q] += e * u[bl][q];
        }

        // counted wait: retire chunk k+1's loads, keep chunk k+2's in flight
        if (chunk < 14)
            asm volatile("s_waitcnt vmcnt(2) lgkmcnt(0)\n\ts_barrier" ::: "memory");
        else if (chunk == 14)
            asm volatile("s_waitcnt vmcnt(0) lgkmcnt(0)\n\ts_barrier" ::: "memory");
        // chunk 15: last compute -> straight to epilogue, no barrier needed
    }
#undef STAGE

    // Reduce accE over the 16 rows (butterfly d<16 stays within each quarter).
    float va = 0.f;
    #pragma unroll
    for (int bl = 0; bl < 4; ++bl) {
        #pragma unroll
        for (int q = 0; q < 4; ++q) {
            float t = accE[bl][q];
            #pragma unroll
            for (int d = 1; d < 16; d <<= 1) t += __shfl_xor(t, d);
            if (lr == bl * 4 + q) va = t;
        }
    }
    float vz = 0.f;
    #pragma unroll
    for (int bl = 0; bl < 4; ++bl) {
        float t = accZ[bl];
        #pragma unroll
        for (int d = 1; d < 64; d <<= 1) t += __shfl_xor(t, d);
        if (lane == bl) vz = t;
    }
    int b = wv * 4 + (lr >> 2);
    int o = h * 4 + (lr & 3);
    atomicAdd(&E[b * 256 + c * 16 + o], va);
    if (lane < 4) atomicAdd(&Z[(wv * 4 + lane) * 16 + c], vz * 0.25f);
}

// ---------------------------------------------------------------------------
// launch
// ---------------------------------------------------------------------------
extern "C" void kernel_launch(void* const* d_in, const int* in_sizes, int n_in,
                              void* d_out, int out_size, void* d_ws, size_t ws_size,
                              hipStream_t stream) {
    const float* x = (const float*)d_in[0];        // 8192 floats
    const float* W = (const float*)d_in[1];        // 67108864 floats (256 MB)
    float* out = (float*)d_out;                    // 8192 floats
    float* ws = (float*)d_ws;

    float* wsum = ws + 0;          // 4096
    float* E2   = ws + 4096;       // 8192
    float* Z2   = ws + 12288;      // 512
    float* E3   = ws + 12800;      // 8192
    float* Z3   = ws + 20992;      // 512   (accumulated region ends at 21504)
    float* v1   = ws + 21504;      // 8192
    float* vs   = ws + 29696;      // 8192  (v1 + v2, input to pass 3)

    // zero accumulators with our own kernel
    k_zero<<<84, 256, 0, stream>>>(ws);            // 84*256 = 21504 floats

    // iter 1: uniform softmax -> v1 from Wsum (W pass 1)
    k_wsum<<<1024, 256, 0, stream>>>((const float4*)W, wsum);
    k_v1<<<32, 256, 0, stream>>>(wsum, x, v1);

    // iter 2 fused: L2 = <u, v1>, E2/Z2 accumulated in-pass (W pass 2)
    k_iter<<<dim3(64, 16), 512, 0, stream>>>(W, x, v1, E2, Z2);
    k_vout_vs<<<32, 256, 0, stream>>>(E2, Z2, v1, vs);   // vs = v1 + squash(E2/Z2)

    // iter 3 fused: L3 = <u, v1+v2> (linearity: no history buffer needed)
    k_iter<<<dim3(64, 16), 512, 0, stream>>>(W, x, vs, E3, Z3);
    k_vout<<<32, 256, 0, stream>>>(E3, Z3, out);         // out = squash(E3/Z3)
}

// Round 8
// 266.400 us; speedup vs baseline: 1.3850x; 1.0160x over previous
//
#include <hip/hip_runtime.h>
#include <math.h>

// B=32, R=16384, C=16, IC=16, OC=16, 3 routing iterations.
// x: (B,C,IC) fp32 [8192]; W: (R,C,OC,IC) fp32 [67108864 = 256 MB]; out: (B,C,OC) fp32.
//
// Key algebra: logits are linear in v with the same u_hat each pass:
//   L2 = <u, v1>,  L3 = L2 + <u, v2> = <u, v1 + v2>
// so pass 3 is the SAME kernel as pass 2 fed with vs = v1 + v2 -> no L array.

#define RT 16384

typedef const __attribute__((address_space(1))) void GV;
typedef __attribute__((address_space(3))) void LV;

__device__ __forceinline__ float rfl(float v) {
    return __int_as_float(__builtin_amdgcn_readfirstlane(__float_as_int(v)));
}

// ---------------------------------------------------------------------------
// K0: zero the accumulator region (wsum+E2+Z2+E3+Z3 = 21504 floats).
// ---------------------------------------------------------------------------
__global__ __launch_bounds__(256) void k_zero(float* __restrict__ ws) {
    ws[blockIdx.x * 256 + threadIdx.x] = 0.f;      // grid 84 x 256 = 21504
}

// ---------------------------------------------------------------------------
// K1: wsum[c,o,i] = sum_r W[r,c,o,i].  W = 16,777,216 float4s.
// ---------------------------------------------------------------------------
__global__ __launch_bounds__(256) void k_wsum(const float4* __restrict__ W4,
                                              float* __restrict__ wsum) {
    int gid = blockIdx.x * 256 + threadIdx.x;      // [0, 262144)
    float4 acc = {0.f, 0.f, 0.f, 0.f};
    int idx = gid;
    #pragma unroll
    for (int it = 0; it < 64; ++it) {              // 16777216 / 262144 = 64
        float4 w = W4[idx];
        acc.x += w.x; acc.y += w.y; acc.z += w.z; acc.w += w.w;
        idx += 262144;
    }
    int cls = gid & 1023;                          // (c,o,i4) within an r-block
    atomicAdd(&wsum[cls * 4 + 0], acc.x);
    atomicAdd(&wsum[cls * 4 + 1], acc.y);
    atomicAdd(&wsum[cls * 4 + 2], acc.z);
    atomicAdd(&wsum[cls * 4 + 3], acc.w);
}

// ---------------------------------------------------------------------------
// K2: s1 = (1/R) * wsum . x ;  v1 = squash(s1)  -> v1[b*256 + c*16 + o]
// ---------------------------------------------------------------------------
__global__ __launch_bounds__(256) void k_v1(const float* __restrict__ wsum,
                                            const float* __restrict__ x,
                                            float* __restrict__ v1) {
    int t = blockIdx.x * 256 + threadIdx.x;        // 0..8191
    int o = t & 15, c = (t >> 4) & 15, b = t >> 8;
    const float* xb = x + (b * 16 + c) * 16;
    const float* wr = wsum + (c * 16 + o) * 16;
    float s = 0.f;
    #pragma unroll
    for (int i = 0; i < 16; ++i) s += wr[i] * xb[i];
    s *= (1.0f / 16384.0f);
    float ns = s * s;
    #pragma unroll
    for (int d = 1; d < 16; d <<= 1) ns += __shfl_xor(ns, d);
    v1[t] = s * (sqrtf(ns) / (1.0f + ns));
}

// ---------------------------------------------------------------------------
// K4a: v2 = squash(E/Z); vs = v1 + v2   (input to pass 3)
// ---------------------------------------------------------------------------
__global__ __launch_bounds__(256) void k_vout_vs(const float* __restrict__ E,
                                                 const float* __restrict__ Z,
                                                 const float* __restrict__ v1,
                                                 float* __restrict__ vs) {
    int t = blockIdx.x * 256 + threadIdx.x;        // 0..8191
    float s = E[t] / Z[t >> 4];                    // t>>4 = b*16+c
    float ns = s * s;
    #pragma unroll
    for (int d = 1; d < 16; d <<= 1) ns += __shfl_xor(ns, d);
    vs[t] = v1[t] + s * (sqrtf(ns) / (1.0f + ns));
}

// ---------------------------------------------------------------------------
// K4b: out = squash(E/Z)
// ---------------------------------------------------------------------------
__global__ __launch_bounds__(256) void k_vout(const float* __restrict__ E,
                                              const float* __restrict__ Z,
                                              float* __restrict__ dst) {
    int t = blockIdx.x * 256 + threadIdx.x;        // 0..8191
    float s = E[t] / Z[t >> 4];
    float ns = s * s;
    #pragma unroll
    for (int d = 1; d < 16; d <<= 1) ns += __shfl_xor(ns, d);
    dst[t] = s * (sqrtf(ns) / (1.0f + ns));
}

// ---------------------------------------------------------------------------
// K3: fused routing pass (ring-2, exact 4-blocks/CU residency, counted vmcnt).
//   u[o] = sum_i W[r,c,o,i]*x[b,c,i];  Lv = sum_o u[o]*v[b,c,o]
//   e = exp(Lv);  E[b,c,o] += e*u[o];  Z[b,c] += e
//
// R7 post-mortem: 53 KB ring-3 -> 3 blocks/CU, ragged 1024/768 residency,
// 6 waves/SIMD; both DS (~61us floor) and VALU (~36us floor) pipes ~50% idle.
// This version: ring-2 x 16.25 KB + 2 KB Vl = 35.3 KB -> 4 blocks/CU, the
// ENTIRE 1024-block grid co-resident (zero tail), 8 waves/SIMD (64-VGPR fit
// pinned by __launch_bounds__(512,8); quarter layout proven spill-free @64
// in R5 -- WRITE_SIZE is the canary).  Ring-2 is race-free via TWO cheap
// barriers per chunk, never draining vmcnt:
//   iter k: compute k (slot k&1) -> barrier -> stage k+2 into slot k&1
//           -> s_waitcnt vmcnt(2) [retires chunk k+1's loads; k+2's stay
//           in flight] -> barrier
// Padded rows (65 float4): additive offsets, imm-folded ds_read_b128, same
// verified 0-conflict bank pattern.  Quarter layout: lane=(h,lr), quarter h
// owns o in [4h,4h+4), row lr of a 16-row chunk; x in SGPRs; Lv = p +
// shfl16 + shfl32; accZ counted 4x -> x0.25.
// ---------------------------------------------------------------------------
#define ROWF4  65
#define SLOTF4 (16 * ROWF4)                        // 1040 float4 = 16640 B

__global__ __launch_bounds__(512, 8)
void k_iter(const float* __restrict__ W,
            const float* __restrict__ x,
            const float* __restrict__ v,
            float* __restrict__ E,
            float* __restrict__ Z) {
    __shared__ float4 Wl[2 * SLOTF4];              // 32.5 KB ring of 2 slots
    __shared__ float4 Vl[128];                     // v[b][o] for this c (2 KB)

    int c = blockIdx.y;
    int r0 = blockIdx.x * 256;
    int tid = threadIdx.x, wv = tid >> 6, lane = tid & 63;
    int h = lane >> 4, lr = lane & 15;             // o-quarter, row-in-chunk

    const float4* W4c = (const float4*)W + (size_t)c * 64;   // row r at +r*1024

    if (tid < 128) {                               // stage v block: Vl[b*4+j]
        int b = tid >> 2, j = tid & 3;
        Vl[tid] = ((const float4*)(v + (b * 16 + c) * 16))[j];
    }

    // x rows for this wave's 4 b's -> SGPRs (wave-uniform)
    float xs[4][16];
    #pragma unroll
    for (int bl = 0; bl < 4; ++bl) {
        const float4* xb = (const float4*)(x + ((wv * 4 + bl) * 16 + c) * 16);
        #pragma unroll
        for (int j = 0; j < 4; ++j) {
            float4 xv = xb[j];
            xs[bl][j * 4 + 0] = rfl(xv.x);
            xs[bl][j * 4 + 1] = rfl(xv.y);
            xs[bl][j * 4 + 2] = rfl(xv.z);
            xs[bl][j * 4 + 3] = rfl(xv.w);
        }
    }
    // pin vmcnt=0 so the counted waits below are exact (x/Vl loads retired)
    asm volatile("s_waitcnt vmcnt(0)" ::: "memory");

    float accE[4][4];
    float accZ[4] = {0.f, 0.f, 0.f, 0.f};
    #pragma unroll
    for (int bl = 0; bl < 4; ++bl)
        #pragma unroll
        for (int q = 0; q < 4; ++q) accE[bl][q] = 0.f;

    // stage chunk cn (16 rows, 1KB each) into ring slot sl: 2 rows per wave,
    // linear DMA into the padded row (1024B written, 16B pad untouched)
#define STAGE(sl, cn) {                                                        \
        int rb = r0 + (cn) * 16;                                               \
        _Pragma("unroll")                                                      \
        for (int k = 0; k < 2; ++k) {                                          \
            int row = k * 8 + wv;                                              \
            const float4* src = W4c + (size_t)(rb + row) * 1024 + lane;        \
            __builtin_amdgcn_global_load_lds((GV*)src,                         \
                (LV*)&Wl[(sl) * SLOTF4 + row * ROWF4], 16, 0, 0);              \
        } }

    // prologue: stage chunks 0,1; wait chunk 0 (vmcnt(2): chunk 1 in flight)
    STAGE(0, 0);
    STAGE(1, 1);
    asm volatile("s_waitcnt vmcnt(2) lgkmcnt(0)\n\ts_barrier" ::: "memory");

    int vidx = lr * ROWF4 + h * 16;                // per-lane read base (f4 idx)

    #pragma unroll
    for (int chunk = 0; chunk < 16; ++chunk) {
        const int sbase = (chunk & 1) * SLOTF4;    // compile-time (full unroll)
        float u[4][4];
        #pragma unroll
        for (int q = 0; q < 4; ++q) {              // q = o within quarter
            float4 w0 = Wl[sbase + vidx + q * 4 + 0];   // imm-offset ds_read_b128
            float4 w1 = Wl[sbase + vidx + q * 4 + 1];
            float4 w2 = Wl[sbase + vidx + q * 4 + 2];
            float4 w3 = Wl[sbase + vidx + q * 4 + 3];
            #pragma unroll
            for (int bl = 0; bl < 4; ++bl) {
                u[bl][q] =
                    w0.x*xs[bl][0]  + w0.y*xs[bl][1]  + w0.z*xs[bl][2]  + w0.w*xs[bl][3]  +
                    w1.x*xs[bl][4]  + w1.y*xs[bl][5]  + w1.z*xs[bl][6]  + w1.w*xs[bl][7]  +
                    w2.x*xs[bl][8]  + w2.y*xs[bl][9]  + w2.z*xs[bl][10] + w2.w*xs[bl][11] +
                    w3.x*xs[bl][12] + w3.y*xs[bl][13] + w3.z*xs[bl][14] + w3.w*xs[bl][15];
            }
        }

        #pragma unroll
        for (int bl = 0; bl < 4; ++bl) {
            float4 vb = Vl[(wv * 4 + bl) * 4 + h]; // this quarter's 4 v comps
            float p = u[bl][0] * vb.x + u[bl][1] * vb.y +
                      u[bl][2] * vb.z + u[bl][3] * vb.w;
            float t = p + __shfl_xor(p, 16);       // combine 4 o-quarters
            float Lv = t + __shfl_xor(t, 32);
            float e = __expf(Lv);
            accZ[bl] += e;                         // counted 4x (all quarters)
            #pragma unroll
            for (int q = 0; q < 4; ++q) accE[bl][q] += e * u[bl][q];
        }

        // slot k&1 free for chunk k+2 only after ALL waves finished compute k
        if (chunk < 14) {
            asm volatile("s_barrier" ::: "memory");
            STAGE(chunk & 1, chunk + 2);           // refill freed slot
            asm volatile("s_waitcnt vmcnt(2) lgkmcnt(0)\n\ts_barrier" ::: "memory");
        } else if (chunk == 14) {
            // no more staging: drain the last chunk's loads (chunk 15)
            asm volatile("s_waitcnt vmcnt(0) lgkmcnt(0)\n\ts_barrier" ::: "memory");
        }
        // chunk 15: last compute -> straight to epilogue, no barrier needed
    }
#undef STAGE

    // Reduce accE over the 16 rows (butterfly d<16 stays within each quarter).
    float va = 0.f;
    #pragma unroll
    for (int bl = 0; bl < 4; ++bl) {
        #pragma unroll
        for (int q = 0; q < 4; ++q) {
            float t = accE[bl][q];
            #pragma unroll
            for (int d = 1; d < 16; d <<= 1) t += __shfl_xor(t, d);
            if (lr == bl * 4 + q) va = t;
        }
    }
    float vz = 0.f;
    #pragma unroll
    for (int bl = 0; bl < 4; ++bl) {
        float t = accZ[bl];
        #pragma unroll
        for (int d = 1; d < 64; d <<= 1) t += __shfl_xor(t, d);
        if (lane == bl) vz = t;
    }
    int b = wv * 4 + (lr >> 2);
    int o = h * 4 + (lr & 3);
    atomicAdd(&E[b * 256 + c * 16 + o], va);
    if (lane < 4) atomicAdd(&Z[(wv * 4 + lane) * 16 + c], vz * 0.25f);
}

// ---------------------------------------------------------------------------
// launch
// ---------------------------------------------------------------------------
extern "C" void kernel_launch(void* const* d_in, const int* in_sizes, int n_in,
                              void* d_out, int out_size, void* d_ws, size_t ws_size,
                              hipStream_t stream) {
    const float* x = (const float*)d_in[0];        // 8192 floats
    const float* W = (const float*)d_in[1];        // 67108864 floats (256 MB)
    float* out = (float*)d_out;                    // 8192 floats
    float* ws = (float*)d_ws;

    float* wsum = ws + 0;          // 4096
    float* E2   = ws + 4096;       // 8192
    float* Z2   = ws + 12288;      // 512
    float* E3   = ws + 12800;      // 8192
    float* Z3   = ws + 20992;      // 512   (accumulated region ends at 21504)
    float* v1   = ws + 21504;      // 8192
    float* vs   = ws + 29696;      // 8192  (v1 + v2, input to pass 3)

    // zero accumulators with our own kernel
    k_zero<<<84, 256, 0, stream>>>(ws);            // 84*256 = 21504 floats

    // iter 1: uniform softmax -> v1 from Wsum (W pass 1)
    k_wsum<<<1024, 256, 0, stream>>>((const float4*)W, wsum);
    k_v1<<<32, 256, 0, stream>>>(wsum, x, v1);

    // iter 2 fused: L2 = <u, v1>, E2/Z2 accumulated in-pass (W pass 2)
    k_iter<<<dim3(64, 16), 512, 0, stream>>>(W, x, v1, E2, Z2);
    k_vout_vs<<<32, 256, 0, stream>>>(E2, Z2, v1, vs);   // vs = v1 + squash(E2/Z2)

    // iter 3 fused: L3 = <u, v1+v2> (linearity: no history buffer needed)
    k_iter<<<dim3(64, 16), 512, 0, stream>>>(W, x, vs, E3, Z3);
    k_vout<<<32, 256, 0, stream>>>(E3, Z3, out);         // out = squash(E3/Z3)
}

// Round 9
// 254.526 us; speedup vs baseline: 1.4496x; 1.0467x over previous
//
#include <hip/hip_runtime.h>
#include <math.h>

// B=32, R=16384, C=16, IC=16, OC=16, 3 routing iterations.
// x: (B,C,IC) fp32 [8192]; W: (R,C,OC,IC) fp32 [67108864 = 256 MB]; out: (B,C,OC) fp32.
//
// Key algebra: logits are linear in v with the same u_hat each pass:
//   L2 = <u, v1>,  L3 = L2 + <u, v2> = <u, v1 + v2>
// so pass 3 is the SAME kernel as pass 2 fed with vs = v1 + v2 -> no L array.

#define RT 16384

typedef const __attribute__((address_space(1))) void GV;
typedef __attribute__((address_space(3))) void LV;

__device__ __forceinline__ float rfl(float v) {
    return __int_as_float(__builtin_amdgcn_readfirstlane(__float_as_int(v)));
}

// xor-16 cross-lane via ds_swizzle BitMode (imm 0x401F = xor_mask 16, and 0x1F):
// same semantics as __shfl_xor(x,16) (stays within each 32-lane half), but a
// single DS op with an immediate pattern (no v_xor/v_lshl address VALU).
__device__ __forceinline__ float swz16(float v) {
    return __int_as_float(__builtin_amdgcn_ds_swizzle(__float_as_int(v), 0x401F));
}

// ---------------------------------------------------------------------------
// K0: zero the accumulator region (wsum+E2+Z2+E3+Z3 = 21504 floats).
// ---------------------------------------------------------------------------
__global__ __launch_bounds__(256) void k_zero(float* __restrict__ ws) {
    ws[blockIdx.x * 256 + threadIdx.x] = 0.f;      // grid 84 x 256 = 21504
}

// ---------------------------------------------------------------------------
// K1: wsum[c,o,i] = sum_r W[r,c,o,i].  W = 16,777,216 float4s.
// ---------------------------------------------------------------------------
__global__ __launch_bounds__(256) void k_wsum(const float4* __restrict__ W4,
                                              float* __restrict__ wsum) {
    int gid = blockIdx.x * 256 + threadIdx.x;      // [0, 262144)
    float4 acc = {0.f, 0.f, 0.f, 0.f};
    int idx = gid;
    #pragma unroll
    for (int it = 0; it < 64; ++it) {              // 16777216 / 262144 = 64
        float4 w = W4[idx];
        acc.x += w.x; acc.y += w.y; acc.z += w.z; acc.w += w.w;
        idx += 262144;
    }
    int cls = gid & 1023;                          // (c,o,i4) within an r-block
    atomicAdd(&wsum[cls * 4 + 0], acc.x);
    atomicAdd(&wsum[cls * 4 + 1], acc.y);
    atomicAdd(&wsum[cls * 4 + 2], acc.z);
    atomicAdd(&wsum[cls * 4 + 3], acc.w);
}

// ---------------------------------------------------------------------------
// K2: s1 = (1/R) * wsum . x ;  v1 = squash(s1)  -> v1[b*256 + c*16 + o]
// ---------------------------------------------------------------------------
__global__ __launch_bounds__(256) void k_v1(const float* __restrict__ wsum,
                                            const float* __restrict__ x,
                                            float* __restrict__ v1) {
    int t = blockIdx.x * 256 + threadIdx.x;        // 0..8191
    int o = t & 15, c = (t >> 4) & 15, b = t >> 8;
    const float* xb = x + (b * 16 + c) * 16;
    const float* wr = wsum + (c * 16 + o) * 16;
    float s = 0.f;
    #pragma unroll
    for (int i = 0; i < 16; ++i) s += wr[i] * xb[i];
    s *= (1.0f / 16384.0f);
    float ns = s * s;
    #pragma unroll
    for (int d = 1; d < 16; d <<= 1) ns += __shfl_xor(ns, d);
    v1[t] = s * (sqrtf(ns) / (1.0f + ns));
}

// ---------------------------------------------------------------------------
// K4a: v2 = squash(E/Z); vs = v1 + v2   (input to pass 3)
// ---------------------------------------------------------------------------
__global__ __launch_bounds__(256) void k_vout_vs(const float* __restrict__ E,
                                                 const float* __restrict__ Z,
                                                 const float* __restrict__ v1,
                                                 float* __restrict__ vs) {
    int t = blockIdx.x * 256 + threadIdx.x;        // 0..8191
    float s = E[t] / Z[t >> 4];                    // t>>4 = b*16+c
    float ns = s * s;
    #pragma unroll
    for (int d = 1; d < 16; d <<= 1) ns += __shfl_xor(ns, d);
    vs[t] = v1[t] + s * (sqrtf(ns) / (1.0f + ns));
}

// ---------------------------------------------------------------------------
// K4b: out = squash(E/Z)
// ---------------------------------------------------------------------------
__global__ __launch_bounds__(256) void k_vout(const float* __restrict__ E,
                                              const float* __restrict__ Z,
                                              float* __restrict__ dst) {
    int t = blockIdx.x * 256 + threadIdx.x;        // 0..8191
    float s = E[t] / Z[t >> 4];
    float ns = s * s;
    #pragma unroll
    for (int d = 1; d < 16; d <<= 1) ns += __shfl_xor(ns, d);
    dst[t] = s * (sqrtf(ns) / (1.0f + ns));
}

// ---------------------------------------------------------------------------
// K3: fused routing pass (R8 skeleton + T5 setprio + batched softmax).
//   u[o] = sum_i W[r,c,o,i]*x[b,c,i];  Lv = sum_o u[o]*v[b,c,o]
//   e = exp(Lv);  E[b,c,o] += e*u[o];  Z[b,c] += e
//
// R8 post-mortem: occupancy 2/3/4 blk/CU, barrier count, and addressing all
// converge at ~120us/pass -> the stall is the per-chunk serial chain
// (u -> p -> shfl16 -> shfl32 -> exp -> accE).  This round:
//   - s_setprio(1) around the compute cluster (T5; counted-vmcnt ring is the
//     phase-split regime where it paid on GEMM)
//   - batched softmax: all 4 p, then all 4 xor16, all 4 xor32, all 4 exp --
//     the two ~40cyc cross-lane latencies overlap 4-wide
//   - xor16 via ds_swizzle imm (no bpermute addr VALU); xor32 stays shfl
//   - lgkmcnt(0) added to the pre-stage barrier (closes the ds_read-in-flight
//     vs DMA-overwrite race R8 was winning by timing luck)
// Geometry unchanged: ring-2 x 16.25KB padded slots + 2KB Vl = 34.5KB ->
// 4 blocks/CU, 64-VGPR tier (launch_bounds(512,8)), quarter layout, counted
// vmcnt(2) distance-2 prefetch, grid (64,16) fully co-resident.
// ---------------------------------------------------------------------------
#define ROWF4  65
#define SLOTF4 (16 * ROWF4)                        // 1040 float4 = 16640 B

__global__ __launch_bounds__(512, 8)
void k_iter(const float* __restrict__ W,
            const float* __restrict__ x,
            const float* __restrict__ v,
            float* __restrict__ E,
            float* __restrict__ Z) {
    __shared__ float4 Wl[2 * SLOTF4];              // 32.5 KB ring of 2 slots
    __shared__ float4 Vl[128];                     // v[b][o] for this c (2 KB)

    int c = blockIdx.y;
    int r0 = blockIdx.x * 256;
    int tid = threadIdx.x, wv = tid >> 6, lane = tid & 63;
    int h = lane >> 4, lr = lane & 15;             // o-quarter, row-in-chunk

    const float4* W4c = (const float4*)W + (size_t)c * 64;   // row r at +r*1024

    if (tid < 128) {                               // stage v block: Vl[b*4+j]
        int b = tid >> 2, j = tid & 3;
        Vl[tid] = ((const float4*)(v + (b * 16 + c) * 16))[j];
    }

    // x rows for this wave's 4 b's -> SGPRs (wave-uniform)
    float xs[4][16];
    #pragma unroll
    for (int bl = 0; bl < 4; ++bl) {
        const float4* xb = (const float4*)(x + ((wv * 4 + bl) * 16 + c) * 16);
        #pragma unroll
        for (int j = 0; j < 4; ++j) {
            float4 xv = xb[j];
            xs[bl][j * 4 + 0] = rfl(xv.x);
            xs[bl][j * 4 + 1] = rfl(xv.y);
            xs[bl][j * 4 + 2] = rfl(xv.z);
            xs[bl][j * 4 + 3] = rfl(xv.w);
        }
    }
    // pin vmcnt=0 so the counted waits below are exact (x/Vl loads retired)
    asm volatile("s_waitcnt vmcnt(0)" ::: "memory");

    float accE[4][4];
    float accZ[4] = {0.f, 0.f, 0.f, 0.f};
    #pragma unroll
    for (int bl = 0; bl < 4; ++bl)
        #pragma unroll
        for (int q = 0; q < 4; ++q) accE[bl][q] = 0.f;

    // stage chunk cn (16 rows, 1KB each) into ring slot sl: 2 rows per wave,
    // linear DMA into the padded row (1024B written, 16B pad untouched)
#define STAGE(sl, cn) {                                                        \
        int rb = r0 + (cn) * 16;                                               \
        _Pragma("unroll")                                                      \
        for (int k = 0; k < 2; ++k) {                                          \
            int row = k * 8 + wv;                                              \
            const float4* src = W4c + (size_t)(rb + row) * 1024 + lane;        \
            __builtin_amdgcn_global_load_lds((GV*)src,                         \
                (LV*)&Wl[(sl) * SLOTF4 + row * ROWF4], 16, 0, 0);              \
        } }

    // prologue: stage chunks 0,1; wait chunk 0 (vmcnt(2): chunk 1 in flight)
    STAGE(0, 0);
    STAGE(1, 1);
    asm volatile("s_waitcnt vmcnt(2) lgkmcnt(0)\n\ts_barrier" ::: "memory");

    int vidx = lr * ROWF4 + h * 16;                // per-lane read base (f4 idx)

    #pragma unroll
    for (int chunk = 0; chunk < 16; ++chunk) {
        const int sbase = (chunk & 1) * SLOTF4;    // compile-time (full unroll)

        __builtin_amdgcn_s_setprio(1);             // favor compute waves (T5)

        // early vb reads (latency hides under the u-FMA block)
        float4 vb[4];
        #pragma unroll
        for (int bl = 0; bl < 4; ++bl) vb[bl] = Vl[(wv * 4 + bl) * 4 + h];

        float u[4][4];
        #pragma unroll
        for (int q = 0; q < 4; ++q) {              // q = o within quarter
            float4 w0 = Wl[sbase + vidx + q * 4 + 0];   // imm-offset ds_read_b128
            float4 w1 = Wl[sbase + vidx + q * 4 + 1];
            float4 w2 = Wl[sbase + vidx + q * 4 + 2];
            float4 w3 = Wl[sbase + vidx + q * 4 + 3];
            #pragma unroll
            for (int bl = 0; bl < 4; ++bl) {
                u[bl][q] =
                    w0.x*xs[bl][0]  + w0.y*xs[bl][1]  + w0.z*xs[bl][2]  + w0.w*xs[bl][3]  +
                    w1.x*xs[bl][4]  + w1.y*xs[bl][5]  + w1.z*xs[bl][6]  + w1.w*xs[bl][7]  +
                    w2.x*xs[bl][8]  + w2.y*xs[bl][9]  + w2.z*xs[bl][10] + w2.w*xs[bl][11] +
                    w3.x*xs[bl][12] + w3.y*xs[bl][13] + w3.z*xs[bl][14] + w3.w*xs[bl][15];
            }
        }

        // batched softmax: stage the 4 independent bl-chains level by level
        // so the two cross-lane latencies overlap 4-wide.
        float p[4], t16[4], e[4];
        #pragma unroll
        for (int bl = 0; bl < 4; ++bl)
            p[bl] = u[bl][0] * vb[bl].x + u[bl][1] * vb[bl].y +
                    u[bl][2] * vb[bl].z + u[bl][3] * vb[bl].w;
        #pragma unroll
        for (int bl = 0; bl < 4; ++bl) t16[bl] = p[bl] + swz16(p[bl]);
        #pragma unroll
        for (int bl = 0; bl < 4; ++bl) t16[bl] = t16[bl] + __shfl_xor(t16[bl], 32);
        #pragma unroll
        for (int bl = 0; bl < 4; ++bl) e[bl] = __expf(t16[bl]);
        #pragma unroll
        for (int bl = 0; bl < 4; ++bl) {
            accZ[bl] += e[bl];                     // counted 4x (all quarters)
            #pragma unroll
            for (int q = 0; q < 4; ++q) accE[bl][q] += e[bl] * u[bl][q];
        }

        __builtin_amdgcn_s_setprio(0);

        // slot k&1 free for chunk k+2 only after ALL waves finished compute k
        if (chunk < 14) {
            asm volatile("s_waitcnt lgkmcnt(0)\n\ts_barrier" ::: "memory");
            STAGE(chunk & 1, chunk + 2);           // refill freed slot
            asm volatile("s_waitcnt vmcnt(2)\n\ts_barrier" ::: "memory");
        } else if (chunk == 14) {
            // no more staging: drain the last chunk's loads (chunk 15)
            asm volatile("s_waitcnt vmcnt(0) lgkmcnt(0)\n\ts_barrier" ::: "memory");
        }
        // chunk 15: last compute -> straight to epilogue, no barrier needed
    }
#undef STAGE

    // Reduce accE over the 16 rows (butterfly d<16 stays within each quarter).
    float va = 0.f;
    #pragma unroll
    for (int bl = 0; bl < 4; ++bl) {
        #pragma unroll
        for (int q = 0; q < 4; ++q) {
            float t = accE[bl][q];
            #pragma unroll
            for (int d = 1; d < 16; d <<= 1) t += __shfl_xor(t, d);
            if (lr == bl * 4 + q) va = t;
        }
    }
    float vz = 0.f;
    #pragma unroll
    for (int bl = 0; bl < 4; ++bl) {
        float t = accZ[bl];
        #pragma unroll
        for (int d = 1; d < 64; d <<= 1) t += __shfl_xor(t, d);
        if (lane == bl) vz = t;
    }
    int b = wv * 4 + (lr >> 2);
    int o = h * 4 + (lr & 3);
    atomicAdd(&E[b * 256 + c * 16 + o], va);
    if (lane < 4) atomicAdd(&Z[(wv * 4 + lane) * 16 + c], vz * 0.25f);
}

// ---------------------------------------------------------------------------
// launch
// ---------------------------------------------------------------------------
extern "C" void kernel_launch(void* const* d_in, const int* in_sizes, int n_in,
                              void* d_out, int out_size, void* d_ws, size_t ws_size,
                              hipStream_t stream) {
    const float* x = (const float*)d_in[0];        // 8192 floats
    const float* W = (const float*)d_in[1];        // 67108864 floats (256 MB)
    float* out = (float*)d_out;                    // 8192 floats
    float* ws = (float*)d_ws;

    float* wsum = ws + 0;          // 4096
    float* E2   = ws + 4096;       // 8192
    float* Z2   = ws + 12288;      // 512
    float* E3   = ws + 12800;      // 8192
    float* Z3   = ws + 20992;      // 512   (accumulated region ends at 21504)
    float* v1   = ws + 21504;      // 8192
    float* vs   = ws + 29696;      // 8192  (v1 + v2, input to pass 3)

    // zero accumulators with our own kernel
    k_zero<<<84, 256, 0, stream>>>(ws);            // 84*256 = 21504 floats

    // iter 1: uniform softmax -> v1 from Wsum (W pass 1)
    k_wsum<<<1024, 256, 0, stream>>>((const float4*)W, wsum);
    k_v1<<<32, 256, 0, stream>>>(wsum, x, v1);

    // iter 2 fused: L2 = <u, v1>, E2/Z2 accumulated in-pass (W pass 2)
    k_iter<<<dim3(64, 16), 512, 0, stream>>>(W, x, v1, E2, Z2);
    k_vout_vs<<<32, 256, 0, stream>>>(E2, Z2, v1, vs);   // vs = v1 + squash(E2/Z2)

    // iter 3 fused: L3 = <u, v1+v2> (linearity: no history buffer needed)
    k_iter<<<dim3(64, 16), 512, 0, stream>>>(W, x, vs, E3, Z3);
    k_vout<<<32, 256, 0, stream>>>(E3, Z3, out);         // out = squash(E3/Z3)
}

// Round 10
// 214.669 us; speedup vs baseline: 1.7188x; 1.1857x over previous
//
#include <hip/hip_runtime.h>
#include <math.h>

// B=32, R=16384, C=16, IC=16, OC=16, 3 routing iterations.
// x: (B,C,IC) fp32 [8192]; W: (R,C,OC,IC) fp32 [67108864 = 256 MB]; out: (B,C,OC) fp32.
//
// Algebra: logits are linear in v with the same u_hat each pass:
//   L2 = <u, v1>,  L3 = L2 + <u, v2> = <u, v1 + v2>
// so pass 3 is the SAME kernel as pass 2 fed with vs = v1 + v2 -> no L history.
//
// R10: MFMA formulation of k_iter.  u[b,o] = sum_i W[r,c,o,i] x[b,c,i] is a
// matmul: one v_mfma_f32_32x32x16_bf16 per (wave, 2 rows) computes
// M=32 (2r x 16o) x N=32 (ALL b) x K=16 (i).  fp32 fidelity via 2x2-term
// bf16 split (hi = RNE-bf16(w), lo = RNE-bf16(w - hi); all 4 cross products).
// Each wave owns 2 private rows + all 32 b -> W streams global->regs
// directly: NO LDS staging, NO barriers, NO ring (kills the 8x LDS read
// amplification that bounded R3-R9 at ~114us/pass).

typedef __attribute__((ext_vector_type(8)))  short short8;
typedef __attribute__((ext_vector_type(16))) float f32x16;

union FU { short8 s; unsigned int u[4]; };

// Split two fp32 into packed bf16 (hi, lo) pairs: hi = RNE-bf16; lo covers
// the next 16 bits (round-half-up).  Product w*x reconstructed with 4 MFMA
// terms -> residual ~2^-16 relative.
__device__ __forceinline__ void splitpk(float a, float b,
                                        unsigned int& hp, unsigned int& lp) {
    unsigned int ua = __float_as_uint(a), ub = __float_as_uint(b);
    unsigned int ta = ua + 0x7FFFu + ((ua >> 16) & 1u);   // RNE to bf16
    unsigned int tb = ub + 0x7FFFu + ((ub >> 16) & 1u);
    hp = (ta >> 16) | (tb & 0xFFFF0000u);                 // (hi_b<<16)|hi_a
    float ha = __uint_as_float(ta & 0xFFFF0000u);
    float hb = __uint_as_float(tb & 0xFFFF0000u);
    unsigned int la = __float_as_uint(a - ha) + 0x8000u;  // round-half-up
    unsigned int lb = __float_as_uint(b - hb) + 0x8000u;
    lp = (la >> 16) | (lb & 0xFFFF0000u);
}

// ---------------------------------------------------------------------------
// K0: zero the accumulator region (wsum+E2+Z2+E3+Z3 = 21504 floats).
// ---------------------------------------------------------------------------
__global__ __launch_bounds__(256) void k_zero(float* __restrict__ ws) {
    ws[blockIdx.x * 256 + threadIdx.x] = 0.f;      // grid 84 x 256 = 21504
}

// ---------------------------------------------------------------------------
// K1: wsum[c,o,i] = sum_r W[r,c,o,i].  W = 16,777,216 float4s.
// ---------------------------------------------------------------------------
__global__ __launch_bounds__(256) void k_wsum(const float4* __restrict__ W4,
                                              float* __restrict__ wsum) {
    int gid = blockIdx.x * 256 + threadIdx.x;      // [0, 262144)
    float4 acc = {0.f, 0.f, 0.f, 0.f};
    int idx = gid;
    #pragma unroll
    for (int it = 0; it < 64; ++it) {              // 16777216 / 262144 = 64
        float4 w = W4[idx];
        acc.x += w.x; acc.y += w.y; acc.z += w.z; acc.w += w.w;
        idx += 262144;
    }
    int cls = gid & 1023;                          // (c,o,i4) within an r-block
    atomicAdd(&wsum[cls * 4 + 0], acc.x);
    atomicAdd(&wsum[cls * 4 + 1], acc.y);
    atomicAdd(&wsum[cls * 4 + 2], acc.z);
    atomicAdd(&wsum[cls * 4 + 3], acc.w);
}

// ---------------------------------------------------------------------------
// K2: s1 = (1/R) * wsum . x ;  v1 = squash(s1)  -> v1[b*256 + c*16 + o]
// ---------------------------------------------------------------------------
__global__ __launch_bounds__(256) void k_v1(const float* __restrict__ wsum,
                                            const float* __restrict__ x,
                                            float* __restrict__ v1) {
    int t = blockIdx.x * 256 + threadIdx.x;        // 0..8191
    int o = t & 15, c = (t >> 4) & 15, b = t >> 8;
    const float* xb = x + (b * 16 + c) * 16;
    const float* wr = wsum + (c * 16 + o) * 16;
    float s = 0.f;
    #pragma unroll
    for (int i = 0; i < 16; ++i) s += wr[i] * xb[i];
    s *= (1.0f / 16384.0f);
    float ns = s * s;
    #pragma unroll
    for (int d = 1; d < 16; d <<= 1) ns += __shfl_xor(ns, d);
    v1[t] = s * (sqrtf(ns) / (1.0f + ns));
}

// ---------------------------------------------------------------------------
// K4a: v2 = squash(E/Z); vs = v1 + v2   (input to pass 3)
// ---------------------------------------------------------------------------
__global__ __launch_bounds__(256) void k_vout_vs(const float* __restrict__ E,
                                                 const float* __restrict__ Z,
                                                 const float* __restrict__ v1,
                                                 float* __restrict__ vs) {
    int t = blockIdx.x * 256 + threadIdx.x;        // 0..8191
    float s = E[t] / Z[t >> 4];                    // t>>4 = b*16+c
    float ns = s * s;
    #pragma unroll
    for (int d = 1; d < 16; d <<= 1) ns += __shfl_xor(ns, d);
    vs[t] = v1[t] + s * (sqrtf(ns) / (1.0f + ns));
}

// ---------------------------------------------------------------------------
// K4b: out = squash(E/Z)
// ---------------------------------------------------------------------------
__global__ __launch_bounds__(256) void k_vout(const float* __restrict__ E,
                                              const float* __restrict__ Z,
                                              float* __restrict__ dst) {
    int t = blockIdx.x * 256 + threadIdx.x;        // 0..8191
    float s = E[t] / Z[t >> 4];
    float ns = s * s;
    #pragma unroll
    for (int d = 1; d < 16; d <<= 1) ns += __shfl_xor(ns, d);
    dst[t] = s * (sqrtf(ns) / (1.0f + ns));
}

// ---------------------------------------------------------------------------
// K3: MFMA routing pass.  Per (wave, chunk): rows {rb, rb+1}, all 32 b.
//   A (M=32 x K=16) = Wsplit[(r',o)][i]:  lane m=l&31 -> r'=m>>4, o=m&15;
//                     k-slice i = 8*(l>>5)+j  (j=0..7, one f4-pair load)
//   B (K=16 x N=32) = Xsplit[i][b]: lane n=l&31=b, same k-slice. Chunk-inv.
//   C (32 x 32): col = lane&31 = b; row = (reg&3)+8*(reg>>2)+4*(lane>>5)
//                = r'*16+o  [m74/m101 verified layout]; regs 0-7 -> r'=0.
//   Lv[b,r'] = sum_o u*v: 8 in-lane FMAs + ONE shfl_xor(32) (partner lane
//   holds the complementary 8 o's).  accE[reg] += e(r')*u; accZ += e0+e1
//   (pair-duplicated -> only lanes <32 emit Z).
// Epilogue: fold r' in-reg, cross-wave reduce via ds_add_f32 into E_lds[512],
// then one global atomic per thread (contention 64-way per slot, as before).
// No main-loop barriers; W prefetched 1 chunk ahead in regs.
// ---------------------------------------------------------------------------
__global__ __launch_bounds__(512)
void k_iter(const float* __restrict__ W,
            const float* __restrict__ x,
            const float* __restrict__ v,
            float* __restrict__ E,
            float* __restrict__ Z) {
    __shared__ float sV[512];                      // v[b][o] for this c
    __shared__ float E_lds[512];                   // block-level E[b][o]
    __shared__ float Z_lds[32];

    int c = blockIdx.y;
    int r0 = blockIdx.x * 256;
    int tid = threadIdx.x, wv = tid >> 6, l = tid & 63;
    int m  = l & 31;                               // A-row group / b for B,C
    int hi = l >> 5;                               // k-slice select

    // stage v + zero the block reduction buffers
    { int b = tid >> 4, o = tid & 15;
      sV[tid] = v[b * 256 + c * 16 + o];
      E_lds[tid] = 0.f; }
    if (tid < 32) Z_lds[tid] = 0.f;

    // B-fragment (x), chunk-invariant: lane b=m, i = 8*hi + 0..7
    FU bh, bl;
    {
        const float4* xb = (const float4*)x + m * 64 + c * 4 + hi * 2;
        float4 x0 = xb[0], x1 = xb[1];
        splitpk(x0.x, x0.y, bh.u[0], bl.u[0]);
        splitpk(x0.z, x0.w, bh.u[1], bl.u[1]);
        splitpk(x1.x, x1.y, bh.u[2], bl.u[2]);
        splitpk(x1.z, x1.w, bh.u[3], bl.u[3]);
    }
    __syncthreads();

    // v-fragment matching C rows: vf[reg] = v[b = m][o(reg)]
    float vf[16];
    #pragma unroll
    for (int reg = 0; reg < 16; ++reg) {
        int o = (reg & 3) + 4 * hi + 8 * ((reg >> 2) & 1);
        vf[reg] = sV[m * 16 + o];
    }

    float accE[16];
    #pragma unroll
    for (int reg = 0; reg < 16; ++reg) accE[reg] = 0.f;
    float accZ = 0.f;

    // W stream base: r = r0 + wv*2 + (m>>4) + 16*chunk; f4 idx =
    // r*1024 + c*64 + (m&15)*4 + hi*2 + {0,1}
    const float4* Wb = (const float4*)W +
        ((size_t)(r0 + wv * 2 + (m >> 4)) * 1024 + c * 64 + (m & 15) * 4 + hi * 2);

    float4 ca = Wb[0], cb = Wb[1];                 // chunk 0 in flight

    #pragma unroll
    for (int chunk = 0; chunk < 16; ++chunk) {
        float4 na = ca, nb = cb;
        if (chunk < 15) {                          // prefetch next chunk
            na = Wb[(size_t)(chunk + 1) * 16384];
            nb = Wb[(size_t)(chunk + 1) * 16384 + 1];
        }

        // split W -> A-fragments (hi, lo)
        FU ah, al;
        splitpk(ca.x, ca.y, ah.u[0], al.u[0]);
        splitpk(ca.z, ca.w, ah.u[1], al.u[1]);
        splitpk(cb.x, cb.y, ah.u[2], al.u[2]);
        splitpk(cb.z, cb.w, ah.u[3], al.u[3]);

        // u = W.x via 4-term bf16 split (smallest term first)
        f32x16 cf;
        #pragma unroll
        for (int i = 0; i < 16; ++i) cf[i] = 0.f;
        cf = __builtin_amdgcn_mfma_f32_32x32x16_bf16(al.s, bl.s, cf, 0, 0, 0);
        cf = __builtin_amdgcn_mfma_f32_32x32x16_bf16(ah.s, bl.s, cf, 0, 0, 0);
        cf = __builtin_amdgcn_mfma_f32_32x32x16_bf16(al.s, bh.s, cf, 0, 0, 0);
        cf = __builtin_amdgcn_mfma_f32_32x32x16_bf16(ah.s, bh.s, cf, 0, 0, 0);

        // softmax: Lv[b, r'] = sum_o u*v;  regs 0-7 are r'=0, 8-15 r'=1
        float Lp0 = 0.f, Lp1 = 0.f;
        #pragma unroll
        for (int reg = 0; reg < 8; ++reg)  Lp0 += cf[reg] * vf[reg];
        #pragma unroll
        for (int reg = 8; reg < 16; ++reg) Lp1 += cf[reg] * vf[reg];
        float Lv0 = Lp0 + __shfl_xor(Lp0, 32);     // partner has other 8 o's
        float Lv1 = Lp1 + __shfl_xor(Lp1, 32);
        float e0 = __expf(Lv0), e1 = __expf(Lv1);
        accZ += e0 + e1;                           // pair-duplicated (l<32 emits)
        #pragma unroll
        for (int reg = 0; reg < 8; ++reg)  accE[reg] += e0 * cf[reg];
        #pragma unroll
        for (int reg = 8; reg < 16; ++reg) accE[reg] += e1 * cf[reg];

        ca = na; cb = nb;
    }

    // fold r' pairs (same o), reduce across waves via LDS atomics
    #pragma unroll
    for (int j = 0; j < 8; ++j) {
        int o = (j & 3) + 4 * hi + 8 * (j >> 2);
        atomicAdd(&E_lds[m * 16 + o], accE[j] + accE[j + 8]);
    }
    if (l < 32) atomicAdd(&Z_lds[m], accZ);
    __syncthreads();

    atomicAdd(&E[(tid >> 4) * 256 + c * 16 + (tid & 15)], E_lds[tid]);
    if (tid < 32) atomicAdd(&Z[tid * 16 + c], Z_lds[tid]);
}

// ---------------------------------------------------------------------------
// launch
// ---------------------------------------------------------------------------
extern "C" void kernel_launch(void* const* d_in, const int* in_sizes, int n_in,
                              void* d_out, int out_size, void* d_ws, size_t ws_size,
                              hipStream_t stream) {
    const float* x = (const float*)d_in[0];        // 8192 floats
    const float* W = (const float*)d_in[1];        // 67108864 floats (256 MB)
    float* out = (float*)d_out;                    // 8192 floats
    float* ws = (float*)d_ws;

    float* wsum = ws + 0;          // 4096
    float* E2   = ws + 4096;       // 8192
    float* Z2   = ws + 12288;      // 512
    float* E3   = ws + 12800;      // 8192
    float* Z3   = ws + 20992;      // 512   (accumulated region ends at 21504)
    float* v1   = ws + 21504;      // 8192
    float* vs   = ws + 29696;      // 8192  (v1 + v2, input to pass 3)

    // zero accumulators with our own kernel
    k_zero<<<84, 256, 0, stream>>>(ws);            // 84*256 = 21504 floats

    // iter 1: uniform softmax -> v1 from Wsum (W pass 1)
    k_wsum<<<1024, 256, 0, stream>>>((const float4*)W, wsum);
    k_v1<<<32, 256, 0, stream>>>(wsum, x, v1);

    // iter 2 fused: L2 = <u, v1>, E2/Z2 accumulated in-pass (W pass 2)
    k_iter<<<dim3(64, 16), 512, 0, stream>>>(W, x, v1, E2, Z2);
    k_vout_vs<<<32, 256, 0, stream>>>(E2, Z2, v1, vs);   // vs = v1 + squash(E2/Z2)

    // iter 3 fused: L3 = <u, v1+v2> (linearity: no history buffer needed)
    k_iter<<<dim3(64, 16), 512, 0, stream>>>(W, x, vs, E3, Z3);
    k_vout<<<32, 256, 0, stream>>>(E3, Z3, out);         // out = squash(E3/Z3)
}

// Round 11
// 204.210 us; speedup vs baseline: 1.8068x; 1.0512x over previous
//
#include <hip/hip_runtime.h>
#include <math.h>

// B=32, R=16384, C=16, IC=16, OC=16, 3 routing iterations.
// x: (B,C,IC) fp32 [8192]; W: (R,C,OC,IC) fp32 [67108864 = 256 MB]; out: (B,C,OC) fp32.
//
// Algebra: logits are linear in v with the same u_hat each pass:
//   L2 = <u, v1>,  L3 = L2 + <u, v2> = <u, v1 + v2>
// so pass 3 is the SAME kernel as pass 2 fed with vs = v1 + v2 -> no L history.
//
// R11: MFMA + DMA-deep wave-private staging.  R10's register streaming had
// only 32 B/wave in flight -> latency-bound at ~95us vs the ~30-42us memory
// floor.  Each wave reads ONLY its own 2 rows/chunk (MFMA A-fragment), so W
// is staged via global_load_lds into per-wave PRIVATE LDS FIFO regions with
// the fragment permutation applied to the GLOBAL source address (linear LDS
// dest).  vmcnt is per-wave -> data-ready needs NO barrier; the main loop has
// ZERO __syncthreads.  Ring-4 x 16KB, distance-3: 6 KB/wave (96 KB/CU) in
// flight -> HBM-saturating.  ds_read pattern [wv][n][lane] = even 8-lane/
// granule-group (optimal b128).

typedef __attribute__((ext_vector_type(8)))  short short8;
typedef __attribute__((ext_vector_type(16))) float f32x16;

union FU { short8 s; unsigned int u[4]; };

typedef const __attribute__((address_space(1))) void GV;
typedef __attribute__((address_space(3))) void LV;

// Split two fp32 into packed bf16 (hi, lo) pairs: hi = RNE-bf16; lo covers
// the next 16 bits (round-half-up).  Product w*x reconstructed with 4 MFMA
// terms -> residual ~2^-16 relative.
__device__ __forceinline__ void splitpk(float a, float b,
                                        unsigned int& hp, unsigned int& lp) {
    unsigned int ua = __float_as_uint(a), ub = __float_as_uint(b);
    unsigned int ta = ua + 0x7FFFu + ((ua >> 16) & 1u);   // RNE to bf16
    unsigned int tb = ub + 0x7FFFu + ((ub >> 16) & 1u);
    hp = (ta >> 16) | (tb & 0xFFFF0000u);                 // (hi_b<<16)|hi_a
    float ha = __uint_as_float(ta & 0xFFFF0000u);
    float hb = __uint_as_float(tb & 0xFFFF0000u);
    unsigned int la = __float_as_uint(a - ha) + 0x8000u;  // round-half-up
    unsigned int lb = __float_as_uint(b - hb) + 0x8000u;
    lp = (la >> 16) | (lb & 0xFFFF0000u);
}

// ---------------------------------------------------------------------------
// K0: zero the accumulator region (wsum+E2+Z2+E3+Z3 = 21504 floats).
// ---------------------------------------------------------------------------
__global__ __launch_bounds__(256) void k_zero(float* __restrict__ ws) {
    ws[blockIdx.x * 256 + threadIdx.x] = 0.f;      // grid 84 x 256 = 21504
}

// ---------------------------------------------------------------------------
// K1: wsum[c,o,i] = sum_r W[r,c,o,i].  W = 16,777,216 float4s.
// ---------------------------------------------------------------------------
__global__ __launch_bounds__(256) void k_wsum(const float4* __restrict__ W4,
                                              float* __restrict__ wsum) {
    int gid = blockIdx.x * 256 + threadIdx.x;      // [0, 262144)
    float4 acc = {0.f, 0.f, 0.f, 0.f};
    int idx = gid;
    #pragma unroll
    for (int it = 0; it < 64; ++it) {              // 16777216 / 262144 = 64
        float4 w = W4[idx];
        acc.x += w.x; acc.y += w.y; acc.z += w.z; acc.w += w.w;
        idx += 262144;
    }
    int cls = gid & 1023;                          // (c,o,i4) within an r-block
    atomicAdd(&wsum[cls * 4 + 0], acc.x);
    atomicAdd(&wsum[cls * 4 + 1], acc.y);
    atomicAdd(&wsum[cls * 4 + 2], acc.z);
    atomicAdd(&wsum[cls * 4 + 3], acc.w);
}

// ---------------------------------------------------------------------------
// K2: s1 = (1/R) * wsum . x ;  v1 = squash(s1)  -> v1[b*256 + c*16 + o]
// ---------------------------------------------------------------------------
__global__ __launch_bounds__(256) void k_v1(const float* __restrict__ wsum,
                                            const float* __restrict__ x,
                                            float* __restrict__ v1) {
    int t = blockIdx.x * 256 + threadIdx.x;        // 0..8191
    int o = t & 15, c = (t >> 4) & 15, b = t >> 8;
    const float* xb = x + (b * 16 + c) * 16;
    const float* wr = wsum + (c * 16 + o) * 16;
    float s = 0.f;
    #pragma unroll
    for (int i = 0; i < 16; ++i) s += wr[i] * xb[i];
    s *= (1.0f / 16384.0f);
    float ns = s * s;
    #pragma unroll
    for (int d = 1; d < 16; d <<= 1) ns += __shfl_xor(ns, d);
    v1[t] = s * (sqrtf(ns) / (1.0f + ns));
}

// ---------------------------------------------------------------------------
// K4a: v2 = squash(E/Z); vs = v1 + v2   (input to pass 3)
// ---------------------------------------------------------------------------
__global__ __launch_bounds__(256) void k_vout_vs(const float* __restrict__ E,
                                                 const float* __restrict__ Z,
                                                 const float* __restrict__ v1,
                                                 float* __restrict__ vs) {
    int t = blockIdx.x * 256 + threadIdx.x;        // 0..8191
    float s = E[t] / Z[t >> 4];                    // t>>4 = b*16+c
    float ns = s * s;
    #pragma unroll
    for (int d = 1; d < 16; d <<= 1) ns += __shfl_xor(ns, d);
    vs[t] = v1[t] + s * (sqrtf(ns) / (1.0f + ns));
}

// ---------------------------------------------------------------------------
// K4b: out = squash(E/Z)
// ---------------------------------------------------------------------------
__global__ __launch_bounds__(256) void k_vout(const float* __restrict__ E,
                                              const float* __restrict__ Z,
                                              float* __restrict__ dst) {
    int t = blockIdx.x * 256 + threadIdx.x;        // 0..8191
    float s = E[t] / Z[t >> 4];
    float ns = s * s;
    #pragma unroll
    for (int d = 1; d < 16; d <<= 1) ns += __shfl_xor(ns, d);
    dst[t] = s * (sqrtf(ns) / (1.0f + ns));
}

// ---------------------------------------------------------------------------
// K3: MFMA routing pass, DMA-deep wave-private pipeline.
//   Per (wave, chunk): rows {rb, rb+1}, all 32 b.
//   A (M=32 x K=16): lane m=l&31 -> row m=(r'<<4)|o; k-slice i=8*(l>>5)+j.
//   B (K=16 x N=32): lane n=b, chunk-invariant (x in regs).
//   C: col=lane&31=b; row=(reg&3)+8*(reg>>2)+4*(l>>5)  [verified R10].
//   Lv[b,r'] = 8 in-lane FMAs + ONE shfl_xor(32).
// Staging: STAGE(slot,chunk) = 2 global_load_lds/wave; LDS layout
// [slot][wv][n][lane] (f4 idx = slot*1024 + wv*128 + n*64 + l) -- source is
// per-lane fragment-permuted, dest linear.  Wave w reads ONLY [.][w][.][.]
// -> vmcnt (per-wave) alone orders data-ready; NO main-loop barriers.
// Ring-4, distance-3, fully unrolled -> exact vmcnt(6/4/2/0) tail.
// Epilogue unchanged: fold r', ds-atomics to E_lds, one global atomic/thread.
// ---------------------------------------------------------------------------
__global__ __launch_bounds__(512)
void k_iter(const float* __restrict__ W,
            const float* __restrict__ x,
            const float* __restrict__ v,
            float* __restrict__ E,
            float* __restrict__ Z) {
    __shared__ float4 Wr[4 * 1024];                // 64 KB: 4 slots x 8 wv x 2 x 64
    __shared__ float sV[512];                      // v[b][o] for this c
    __shared__ float E_lds[512];                   // block-level E[b][o]
    __shared__ float Z_lds[32];

    int c = blockIdx.y;
    int r0 = blockIdx.x * 256;
    int tid = threadIdx.x, wv = tid >> 6, l = tid & 63;
    int m  = l & 31;                               // A-row / b-col
    int hi = l >> 5;                               // k-slice select

    // stage v + zero the block reduction buffers
    { int b = tid >> 4, o = tid & 15;
      sV[tid] = v[b * 256 + c * 16 + o];
      E_lds[tid] = 0.f; }
    if (tid < 32) Z_lds[tid] = 0.f;

    // B-fragment (x), chunk-invariant: lane b=m, i = 8*hi + 0..7
    FU bh, bl;
    {
        const float4* xb = (const float4*)x + m * 64 + c * 4 + hi * 2;
        float4 x0 = xb[0], x1 = xb[1];
        splitpk(x0.x, x0.y, bh.u[0], bl.u[0]);
        splitpk(x0.z, x0.w, bh.u[1], bl.u[1]);
        splitpk(x1.x, x1.y, bh.u[2], bl.u[2]);
        splitpk(x1.z, x1.w, bh.u[3], bl.u[3]);
    }
    __syncthreads();                               // sV ready (written cross-lane)

    // v-fragment matching C rows: vf[reg] = v[b = m][o(reg)]
    float vf[16];
    #pragma unroll
    for (int reg = 0; reg < 16; ++reg) {
        int o = (reg & 3) + 4 * hi + 8 * ((reg >> 2) & 1);
        vf[reg] = sV[m * 16 + o];
    }

    float accE[16];
    #pragma unroll
    for (int reg = 0; reg < 16; ++reg) accE[reg] = 0.f;
    float accZ = 0.f;

    // pin vmcnt=0 so the counted waits below are exact (x/sV loads retired)
    asm volatile("s_waitcnt vmcnt(0)" ::: "memory");

    const float4* W4c = (const float4*)W + (size_t)c * 64;   // row r at +r*1024

    // STAGE: wave wv stages its OWN 2 rows of chunk cn into slot sl.
    // src (per-lane, fragment-permuted): row = rb + wv*2 + (m>>4),
    //   f4 = (m&15)*4 + hi*2 + n;   dest (linear): [sl][wv][n][lane].
#define STAGE(sl, cn) {                                                        \
        const float4* s0 = W4c +                                               \
            (size_t)(r0 + (cn) * 16 + wv * 2 + (m >> 4)) * 1024 +              \
            (m & 15) * 4 + hi * 2;                                             \
        __builtin_amdgcn_global_load_lds((GV*)s0,                              \
            (LV*)&Wr[(sl) * 1024 + wv * 128], 16, 0, 0);                       \
        __builtin_amdgcn_global_load_lds((GV*)(s0 + 1),                        \
            (LV*)&Wr[(sl) * 1024 + wv * 128 + 64], 16, 0, 0);                  \
    }

    STAGE(0, 0); STAGE(1, 1); STAGE(2, 2);         // 6 issues in flight

    #pragma unroll
    for (int chunk = 0; chunk < 16; ++chunk) {
        if (chunk <= 12) STAGE((chunk + 3) & 3, chunk + 3);

        // retire THIS wave's loads for chunk k; deeper prefetches stay in flight
        if (chunk <= 12)      asm volatile("s_waitcnt vmcnt(6)" ::: "memory");
        else if (chunk == 13) asm volatile("s_waitcnt vmcnt(4)" ::: "memory");
        else if (chunk == 14) asm volatile("s_waitcnt vmcnt(2)" ::: "memory");
        else                  asm volatile("s_waitcnt vmcnt(0)" ::: "memory");

        int sb = (chunk & 3) * 1024 + wv * 128 + l;
        float4 ca = Wr[sb];                        // ds_read_b128, even 8/group
        float4 cb = Wr[sb + 64];

        // split W -> A-fragments (hi, lo)
        FU ah, al;
        splitpk(ca.x, ca.y, ah.u[0], al.u[0]);
        splitpk(ca.z, ca.w, ah.u[1], al.u[1]);
        splitpk(cb.x, cb.y, ah.u[2], al.u[2]);
        splitpk(cb.z, cb.w, ah.u[3], al.u[3]);

        // u = W.x via 4-term bf16 split (smallest term first)
        f32x16 cf;
        #pragma unroll
        for (int i = 0; i < 16; ++i) cf[i] = 0.f;
        cf = __builtin_amdgcn_mfma_f32_32x32x16_bf16(al.s, bl.s, cf, 0, 0, 0);
        cf = __builtin_amdgcn_mfma_f32_32x32x16_bf16(ah.s, bl.s, cf, 0, 0, 0);
        cf = __builtin_amdgcn_mfma_f32_32x32x16_bf16(al.s, bh.s, cf, 0, 0, 0);
        cf = __builtin_amdgcn_mfma_f32_32x32x16_bf16(ah.s, bh.s, cf, 0, 0, 0);

        // softmax: Lv[b, r'] = sum_o u*v;  regs 0-7 are r'=0, 8-15 r'=1
        float Lp0 = 0.f, Lp1 = 0.f;
        #pragma unroll
        for (int reg = 0; reg < 8; ++reg)  Lp0 += cf[reg] * vf[reg];
        #pragma unroll
        for (int reg = 8; reg < 16; ++reg) Lp1 += cf[reg] * vf[reg];
        float Lv0 = Lp0 + __shfl_xor(Lp0, 32);     // partner has other 8 o's
        float Lv1 = Lp1 + __shfl_xor(Lp1, 32);
        float e0 = __expf(Lv0), e1 = __expf(Lv1);
        accZ += e0 + e1;                           // pair-duplicated (l<32 emits)
        #pragma unroll
        for (int reg = 0; reg < 8; ++reg)  accE[reg] += e0 * cf[reg];
        #pragma unroll
        for (int reg = 8; reg < 16; ++reg) accE[reg] += e1 * cf[reg];
    }
#undef STAGE

    // fold r' pairs (same o), reduce across waves via LDS atomics
    #pragma unroll
    for (int j = 0; j < 8; ++j) {
        int o = (j & 3) + 4 * hi + 8 * (j >> 2);
        atomicAdd(&E_lds[m * 16 + o], accE[j] + accE[j + 8]);
    }
    if (l < 32) atomicAdd(&Z_lds[m], accZ);
    __syncthreads();

    atomicAdd(&E[(tid >> 4) * 256 + c * 16 + (tid & 15)], E_lds[tid]);
    if (tid < 32) atomicAdd(&Z[tid * 16 + c], Z_lds[tid]);
}

// ---------------------------------------------------------------------------
// launch
// ---------------------------------------------------------------------------
extern "C" void kernel_launch(void* const* d_in, const int* in_sizes, int n_in,
                              void* d_out, int out_size, void* d_ws, size_t ws_size,
                              hipStream_t stream) {
    const float* x = (const float*)d_in[0];        // 8192 floats
    const float* W = (const float*)d_in[1];        // 67108864 floats (256 MB)
    float* out = (float*)d_out;                    // 8192 floats
    float* ws = (float*)d_ws;

    float* wsum = ws + 0;          // 4096
    float* E2   = ws + 4096;       // 8192
    float* Z2   = ws + 12288;      // 512
    float* E3   = ws + 12800;      // 8192
    float* Z3   = ws + 20992;      // 512   (accumulated region ends at 21504)
    float* v1   = ws + 21504;      // 8192
    float* vs   = ws + 29696;      // 8192  (v1 + v2, input to pass 3)

    // zero accumulators with our own kernel
    k_zero<<<84, 256, 0, stream>>>(ws);            // 84*256 = 21504 floats

    // iter 1: uniform softmax -> v1 from Wsum (W pass 1)
    k_wsum<<<1024, 256, 0, stream>>>((const float4*)W, wsum);
    k_v1<<<32, 256, 0, stream>>>(wsum, x, v1);

    // iter 2 fused: L2 = <u, v1>, E2/Z2 accumulated in-pass (W pass 2)
    k_iter<<<dim3(64, 16), 512, 0, stream>>>(W, x, v1, E2, Z2);
    k_vout_vs<<<32, 256, 0, stream>>>(E2, Z2, v1, vs);   // vs = v1 + squash(E2/Z2)

    // iter 3 fused: L3 = <u, v1+v2> (linearity: no history buffer needed)
    k_iter<<<dim3(64, 16), 512, 0, stream>>>(W, x, vs, E3, Z3);
    k_vout<<<32, 256, 0, stream>>>(E3, Z3, out);         // out = squash(E3/Z3)
}